// Round 8
// baseline (331.569 us; speedup 1.0000x reference)
//
#include <hip/hip_runtime.h>
#include <hip/hip_fp16.h>

#define N_NODES 100000
#define N_EDGES 3200000
#define F_IN 256
#define H1 64
#define H2C 32
#define NCLS 2
#define EPS 1e-5f

#define NBK 391            // ceil(100000/256) buckets of 256 dst nodes
#define BK_CAP 10240       // max edges per bucket (mean 8184, sd ~90; 11+ sigma margin)
#define SCHUNK 16384       // edges per k_bin_scatter block
#define BPP 3125           // agg1 blocks per pass = N*8/256 (exact)

// ---------------- pass 1: per-bucket histogram ----------------
__global__ __launch_bounds__(256) void k_bin_count(const int* __restrict__ dst,
                                                   int* __restrict__ bucket_count) {
    __shared__ int h[NBK];
    for (int i = threadIdx.x; i < NBK; i += 256) h[i] = 0;
    __syncthreads();
    int stride = gridDim.x * 256;
    for (int e = blockIdx.x * 256 + threadIdx.x; e < N_EDGES; e += stride)
        atomicAdd(&h[((unsigned)dst[e]) >> 8], 1);
    __syncthreads();
    for (int i = threadIdx.x; i < NBK; i += 256)
        if (h[i]) atomicAdd(&bucket_count[i], h[i]);
}

// ---------------- pass 2: scan bucket counts ----------------
__global__ void k_bucket_scan(const int* __restrict__ bucket_count,
                              int* __restrict__ bucket_base) {
    __shared__ int s[512];
    int t = threadIdx.x;
    int v = (t < NBK) ? bucket_count[t] : 0;
    s[t] = v;
    __syncthreads();
    for (int off = 1; off < 512; off <<= 1) {
        int x = (t >= off) ? s[t - off] : 0;
        __syncthreads();
        s[t] += x;
        __syncthreads();
    }
    if (t < NBK) bucket_base[t] = s[t] - v;   // exclusive
    if (t == 0) bucket_base[NBK] = N_EDGES;
}

// ---------------- pass 3: scatter edges into bucket-major packed records ----------------
// packed record: (dst & 255) << 24 | src   (src < 100000 < 2^24)
__global__ __launch_bounds__(256) void k_bin_scatter(const int* __restrict__ src,
                                                     const int* __restrict__ dst,
                                                     const int* __restrict__ bucket_base,
                                                     int* __restrict__ cursor,
                                                     int* __restrict__ packed) {
    __shared__ int h[NBK];     // local hist, then local cursor
    __shared__ int base[NBK];  // global run base for this block
    int t = threadIdx.x;
    int e0 = blockIdx.x * SCHUNK;
    int e1 = e0 + SCHUNK; if (e1 > N_EDGES) e1 = N_EDGES;
    for (int i = t; i < NBK; i += 256) h[i] = 0;
    __syncthreads();
    for (int e = e0 + t; e < e1; e += 256)
        atomicAdd(&h[((unsigned)dst[e]) >> 8], 1);
    __syncthreads();
    for (int i = t; i < NBK; i += 256) {
        int c = h[i];
        base[i] = c ? (bucket_base[i] + atomicAdd(&cursor[i], c)) : 0;
        h[i] = 0;
    }
    __syncthreads();
    for (int e = e0 + t; e < e1; e += 256) {
        int d = dst[e];
        int b = ((unsigned)d) >> 8;
        int pos = base[b] + atomicAdd(&h[b], 1);
        packed[pos] = ((d & 255) << 24) | src[e];
    }
}

// ---------------- pass 4: per-bucket CSR build (LDS) + offs + dinv ----------------
__global__ __launch_bounds__(256) void k_csr_build(const int* __restrict__ packed,
                                                   const int* __restrict__ bucket_base,
                                                   int* __restrict__ csr,
                                                   int* __restrict__ offs_g,
                                                   float* __restrict__ dinv) {
    __shared__ int hist[256];
    __shared__ int offs[257];
    __shared__ int csr_l[BK_CAP];
    int t = threadIdx.x;
    int b = blockIdx.x;
    int node0 = b << 8;
    int nn = N_NODES - node0; if (nn > 256) nn = 256;
    int ebase = bucket_base[b];
    int ecnt = bucket_base[b + 1] - ebase;
    if (ecnt > BK_CAP) ecnt = BK_CAP;   // never triggers for this input; LDS safety

    hist[t] = 0;
    __syncthreads();
    for (int i = t; i < ecnt; i += 256)
        atomicAdd(&hist[((unsigned)packed[ebase + i]) >> 24], 1);
    __syncthreads();
    int d = hist[t];
    offs[t] = d;
    __syncthreads();
    for (int off = 1; off < 256; off <<= 1) {
        int x = (t >= off) ? offs[t - off] : 0;
        __syncthreads();
        offs[t] += x;
        __syncthreads();
    }
    int incl = offs[t];
    int excl = incl - d;
    __syncthreads();
    offs[t] = excl;
    if (t == 255) offs[256] = incl;   // == ecnt
    hist[t] = 0;                      // reuse as per-node cursor
    __syncthreads();
    for (int i = t; i < ecnt; i += 256) {
        int p = packed[ebase + i];
        int ld = ((unsigned)p) >> 24;
        int pos = offs[ld] + atomicAdd(&hist[ld], 1);
        csr_l[pos] = p & 0xFFFFFF;
    }
    __syncthreads();
    for (int i = t; i < ecnt; i += 256)
        csr[ebase + i] = csr_l[i];
    if (t < nn) {
        offs_g[node0 + t] = ebase + excl;
        dinv[node0 + t] = rsqrtf((float)d + 1.0f);
    }
    if (b == NBK - 1 && t == 0) offs_g[N_NODES] = N_EDGES;
}

// ---------------- GEMM1: h1q[c>>4][n][c&15] = fp16((x @ W1)[n][c] * dinv[n]) ----------------
__global__ __launch_bounds__(256) void k_gemm1(const float* __restrict__ x,
                                               const float* __restrict__ W1,
                                               const float* __restrict__ dinv,
                                               unsigned short* __restrict__ h1q) {
    __shared__ float xt[32][64];   // [k][node]
    __shared__ float wt[32][64];   // [k][col]
    int t = threadIdx.x;
    int nodeBase = blockIdx.x * 64;
    int ng = t >> 4;        // 0..15 -> node group of 4
    int jg = t & 15;        // 0..15 -> col group of 4
    int ldn = t & 63;       // node for x staging
    int kq  = t >> 6;       // 0..3  -> k-octet for x staging
    int wcol = (t & 15) * 4;
    int kw  = t >> 4;       // 0..15 -> k row for W staging
    float acc[4][4] = {};
    for (int kc = 0; kc < F_IN; kc += 32) {
        int gn = nodeBase + ldn; if (gn >= N_NODES) gn = N_NODES - 1;
        const float* xr = x + (size_t)gn * F_IN + kc + kq * 8;
        float4 a0 = *(const float4*)xr;
        float4 a1 = *(const float4*)(xr + 4);
        int kb = kq * 8;
        xt[kb + 0][ldn] = a0.x; xt[kb + 1][ldn] = a0.y;
        xt[kb + 2][ldn] = a0.z; xt[kb + 3][ldn] = a0.w;
        xt[kb + 4][ldn] = a1.x; xt[kb + 5][ldn] = a1.y;
        xt[kb + 6][ldn] = a1.z; xt[kb + 7][ldn] = a1.w;
        const float* wr = W1 + (size_t)(kc + kw) * H1 + wcol;
        float4 b0 = *(const float4*)wr;
        float4 b1 = *(const float4*)(wr + 16 * H1);
        *(float4*)&wt[kw][wcol] = b0;
        *(float4*)&wt[kw + 16][wcol] = b1;
        __syncthreads();
        #pragma unroll
        for (int k = 0; k < 32; k++) {
            float4 av = *(const float4*)&xt[k][ng * 4];
            float4 bv = *(const float4*)&wt[k][jg * 4];
            acc[0][0] += av.x * bv.x; acc[0][1] += av.x * bv.y; acc[0][2] += av.x * bv.z; acc[0][3] += av.x * bv.w;
            acc[1][0] += av.y * bv.x; acc[1][1] += av.y * bv.y; acc[1][2] += av.y * bv.z; acc[1][3] += av.y * bv.w;
            acc[2][0] += av.z * bv.x; acc[2][1] += av.z * bv.y; acc[2][2] += av.z * bv.z; acc[2][3] += av.z * bv.w;
            acc[3][0] += av.w * bv.x; acc[3][1] += av.w * bv.y; acc[3][2] += av.w * bv.z; acc[3][3] += av.w * bv.w;
        }
        __syncthreads();
    }
    // write to channel-sliced layout: slice q = jg>>2, offset (jg&3)*4
    #pragma unroll
    for (int i = 0; i < 4; i++) {
        int n = nodeBase + ng * 4 + i;
        if (n < N_NODES) {
            float dn = dinv[n];
            ushort4 o;
            o.x = __half_as_ushort(__float2half(acc[i][0] * dn));
            o.y = __half_as_ushort(__float2half(acc[i][1] * dn));
            o.z = __half_as_ushort(__float2half(acc[i][2] * dn));
            o.w = __half_as_ushort(__float2half(acc[i][3] * dn));
            *(ushort4*)&h1q[((size_t)(jg >> 2) * N_NODES + n) * 16 + (jg & 3) * 4] = o;
        }
    }
}

// ---------------- agg1 + BN1 + ReLU: 4 channel-sliced passes, 8 lanes/node, 2 ch/lane ----------------
__global__ __launch_bounds__(256) void k_agg1(const unsigned short* __restrict__ h1q,
                                              const float* __restrict__ dinv,
                                              const int* __restrict__ offs,
                                              const int* __restrict__ csr,
                                              const float* __restrict__ b1,
                                              const float* __restrict__ g1,
                                              const float* __restrict__ be1,
                                              const float* __restrict__ m1,
                                              const float* __restrict__ v1,
                                              unsigned short* __restrict__ out1) {
    int pass = blockIdx.x / BPP;                      // 0..3 -> channel slice (3.2 MB, L2-resident)
    int idx = (blockIdx.x - pass * BPP) * 256 + threadIdx.x;
    int n = idx >> 3;
    int cp = idx & 7;            // channel pair within slice: slice-channels 2cp, 2cp+1
    const ushort2* hp = (const ushort2*)(h1q + (size_t)pass * N_NODES * 16);  // [N][8]
    float sx = 0.f, sy = 0.f;
    int k = offs[n], kend = offs[n + 1];
    for (; k + 7 < kend; k += 8) {
        int s0 = csr[k],     s1 = csr[k + 1], s2 = csr[k + 2], s3 = csr[k + 3];
        int s4 = csr[k + 4], s5 = csr[k + 5], s6 = csr[k + 6], s7 = csr[k + 7];
        ushort2 u0 = hp[(size_t)s0 * 8 + cp], u1 = hp[(size_t)s1 * 8 + cp];
        ushort2 u2 = hp[(size_t)s2 * 8 + cp], u3 = hp[(size_t)s3 * 8 + cp];
        ushort2 u4 = hp[(size_t)s4 * 8 + cp], u5 = hp[(size_t)s5 * 8 + cp];
        ushort2 u6 = hp[(size_t)s6 * 8 + cp], u7 = hp[(size_t)s7 * 8 + cp];
        float2 f0 = __half22float2(*(const __half2*)&u0);
        float2 f1 = __half22float2(*(const __half2*)&u1);
        float2 f2 = __half22float2(*(const __half2*)&u2);
        float2 f3 = __half22float2(*(const __half2*)&u3);
        float2 f4 = __half22float2(*(const __half2*)&u4);
        float2 f5 = __half22float2(*(const __half2*)&u5);
        float2 f6 = __half22float2(*(const __half2*)&u6);
        float2 f7 = __half22float2(*(const __half2*)&u7);
        sx += (f0.x + f1.x) + (f2.x + f3.x) + ((f4.x + f5.x) + (f6.x + f7.x));
        sy += (f0.y + f1.y) + (f2.y + f3.y) + ((f4.y + f5.y) + (f6.y + f7.y));
    }
    if (k < kend) {              // masked 8-wide tail
        int last = kend - 1;
        int i1 = k + 1 <= last ? k + 1 : last;
        int i2 = k + 2 <= last ? k + 2 : last;
        int i3 = k + 3 <= last ? k + 3 : last;
        int i4 = k + 4 <= last ? k + 4 : last;
        int i5 = k + 5 <= last ? k + 5 : last;
        int i6 = k + 6 <= last ? k + 6 : last;
        int s0 = csr[k],  s1 = csr[i1], s2 = csr[i2], s3 = csr[i3];
        int s4 = csr[i4], s5 = csr[i5], s6 = csr[i6];
        ushort2 u0 = hp[(size_t)s0 * 8 + cp], u1 = hp[(size_t)s1 * 8 + cp];
        ushort2 u2 = hp[(size_t)s2 * 8 + cp], u3 = hp[(size_t)s3 * 8 + cp];
        ushort2 u4 = hp[(size_t)s4 * 8 + cp], u5 = hp[(size_t)s5 * 8 + cp];
        ushort2 u6 = hp[(size_t)s6 * 8 + cp];
        float2 f0 = __half22float2(*(const __half2*)&u0);
        float2 f1 = __half22float2(*(const __half2*)&u1);
        float2 f2 = __half22float2(*(const __half2*)&u2);
        float2 f3 = __half22float2(*(const __half2*)&u3);
        float2 f4 = __half22float2(*(const __half2*)&u4);
        float2 f5 = __half22float2(*(const __half2*)&u5);
        float2 f6 = __half22float2(*(const __half2*)&u6);
        float m1v = (k + 1 <= last) ? 1.f : 0.f;
        float m2v = (k + 2 <= last) ? 1.f : 0.f;
        float m3v = (k + 3 <= last) ? 1.f : 0.f;
        float m4v = (k + 4 <= last) ? 1.f : 0.f;
        float m5v = (k + 5 <= last) ? 1.f : 0.f;
        float m6v = (k + 6 <= last) ? 1.f : 0.f;
        sx += f0.x + m1v * f1.x + m2v * f2.x + m3v * f3.x + m4v * f4.x + m5v * f5.x + m6v * f6.x;
        sy += f0.y + m1v * f1.y + m2v * f2.y + m3v * f3.y + m4v * f4.y + m5v * f5.y + m6v * f6.y;
    }
    // self term (pre-scaled by dinv[n])
    ushort2 su = hp[(size_t)n * 8 + cp];
    float2 sf = __half22float2(*(const __half2*)&su);
    float dn = dinv[n];
    int c0 = pass * 16 + cp * 2, c1 = c0 + 1;
    float r0 = (sx + sf.x) * dn + b1[c0];
    float r1 = (sy + sf.y) * dn + b1[c1];
    r0 = (r0 - m1[c0]) * rsqrtf(v1[c0] + EPS) * g1[c0] + be1[c0];
    r1 = (r1 - m1[c1]) * rsqrtf(v1[c1] + EPS) * g1[c1] + be1[c1];
    r0 = fmaxf(r0, 0.f);
    r1 = fmaxf(r1, 0.f);
    ushort2 o;
    o.x = __half_as_ushort(__float2half(r0));
    o.y = __half_as_ushort(__float2half(r1));
    ((ushort2*)out1)[(size_t)n * 32 + pass * 8 + cp] = o;   // out1 is [N][64] interleaved
}

// ---------------- GEMM2: h2s = fp16((out1 @ W2) * dinv[n])  [N,64]@[64,32] ----------------
__global__ __launch_bounds__(256) void k_gemm2(const unsigned short* __restrict__ in,
                                               const float* __restrict__ W2,
                                               const float* __restrict__ dinv,
                                               unsigned short* __restrict__ h2s) {
    __shared__ float w[H1 * H2C];
    int t = threadIdx.x;
    for (int i = t; i < H1 * H2C; i += 256) w[i] = W2[i];
    __syncthreads();
    int idx = blockIdx.x * 256 + t;
    int n = idx >> 5;
    int j = idx & 31;
    if (n >= N_NODES) return;
    const uint4* r4 = (const uint4*)(in + (size_t)n * H1);  // 8 × 16B = row
    float acc = 0.0f;
    #pragma unroll
    for (int q = 0; q < 8; q++) {
        uint4 c = r4[q];
        float2 a0 = __half22float2(*(const __half2*)&c.x);
        float2 a1 = __half22float2(*(const __half2*)&c.y);
        float2 a2 = __half22float2(*(const __half2*)&c.z);
        float2 a3 = __half22float2(*(const __half2*)&c.w);
        int kb = q * 8;
        acc += a0.x * w[(kb + 0) * H2C + j] + a0.y * w[(kb + 1) * H2C + j]
             + a1.x * w[(kb + 2) * H2C + j] + a1.y * w[(kb + 3) * H2C + j]
             + a2.x * w[(kb + 4) * H2C + j] + a2.y * w[(kb + 5) * H2C + j]
             + a3.x * w[(kb + 6) * H2C + j] + a3.y * w[(kb + 7) * H2C + j];
    }
    h2s[(size_t)n * H2C + j] = __half_as_ushort(__float2half(acc * dinv[n]));
}

// ---------------- agg2 + BN2 + ReLU + linear: 16 lanes/node, 2 ch/lane ----------------
__global__ __launch_bounds__(256) void k_agg2(const unsigned short* __restrict__ h2s,
                                              const float* __restrict__ dinv,
                                              const int* __restrict__ offs,
                                              const int* __restrict__ csr,
                                              const float* __restrict__ b2,
                                              const float* __restrict__ g2,
                                              const float* __restrict__ be2,
                                              const float* __restrict__ m2,
                                              const float* __restrict__ v2,
                                              const float* __restrict__ Wl,
                                              const float* __restrict__ bl,
                                              float* __restrict__ out) {
    int gid = blockIdx.x * 256 + threadIdx.x;
    int n = gid >> 4;
    int cp = gid & 15;           // channel pair: channels 2cp, 2cp+1
    if (n >= N_NODES) return;
    const ushort2* hp = (const ushort2*)h2s;   // [N][16]
    float sx = 0.f, sy = 0.f;
    int k = offs[n], kend = offs[n + 1];
    for (; k + 7 < kend; k += 8) {
        int s0 = csr[k],     s1 = csr[k + 1], s2 = csr[k + 2], s3 = csr[k + 3];
        int s4 = csr[k + 4], s5 = csr[k + 5], s6 = csr[k + 6], s7 = csr[k + 7];
        ushort2 u0 = hp[(size_t)s0 * 16 + cp], u1 = hp[(size_t)s1 * 16 + cp];
        ushort2 u2 = hp[(size_t)s2 * 16 + cp], u3 = hp[(size_t)s3 * 16 + cp];
        ushort2 u4 = hp[(size_t)s4 * 16 + cp], u5 = hp[(size_t)s5 * 16 + cp];
        ushort2 u6 = hp[(size_t)s6 * 16 + cp], u7 = hp[(size_t)s7 * 16 + cp];
        float2 f0 = __half22float2(*(const __half2*)&u0);
        float2 f1 = __half22float2(*(const __half2*)&u1);
        float2 f2 = __half22float2(*(const __half2*)&u2);
        float2 f3 = __half22float2(*(const __half2*)&u3);
        float2 f4 = __half22float2(*(const __half2*)&u4);
        float2 f5 = __half22float2(*(const __half2*)&u5);
        float2 f6 = __half22float2(*(const __half2*)&u6);
        float2 f7 = __half22float2(*(const __half2*)&u7);
        sx += (f0.x + f1.x) + (f2.x + f3.x) + ((f4.x + f5.x) + (f6.x + f7.x));
        sy += (f0.y + f1.y) + (f2.y + f3.y) + ((f4.y + f5.y) + (f6.y + f7.y));
    }
    if (k < kend) {              // masked 8-wide tail
        int last = kend - 1;
        int i1 = k + 1 <= last ? k + 1 : last;
        int i2 = k + 2 <= last ? k + 2 : last;
        int i3 = k + 3 <= last ? k + 3 : last;
        int i4 = k + 4 <= last ? k + 4 : last;
        int i5 = k + 5 <= last ? k + 5 : last;
        int i6 = k + 6 <= last ? k + 6 : last;
        int s0 = csr[k],  s1 = csr[i1], s2 = csr[i2], s3 = csr[i3];
        int s4 = csr[i4], s5 = csr[i5], s6 = csr[i6];
        ushort2 u0 = hp[(size_t)s0 * 16 + cp], u1 = hp[(size_t)s1 * 16 + cp];
        ushort2 u2 = hp[(size_t)s2 * 16 + cp], u3 = hp[(size_t)s3 * 16 + cp];
        ushort2 u4 = hp[(size_t)s4 * 16 + cp], u5 = hp[(size_t)s5 * 16 + cp];
        ushort2 u6 = hp[(size_t)s6 * 16 + cp];
        float2 f0 = __half22float2(*(const __half2*)&u0);
        float2 f1 = __half22float2(*(const __half2*)&u1);
        float2 f2 = __half22float2(*(const __half2*)&u2);
        float2 f3 = __half22float2(*(const __half2*)&u3);
        float2 f4 = __half22float2(*(const __half2*)&u4);
        float2 f5 = __half22float2(*(const __half2*)&u5);
        float2 f6 = __half22float2(*(const __half2*)&u6);
        float m1v = (k + 1 <= last) ? 1.f : 0.f;
        float m2v = (k + 2 <= last) ? 1.f : 0.f;
        float m3v = (k + 3 <= last) ? 1.f : 0.f;
        float m4v = (k + 4 <= last) ? 1.f : 0.f;
        float m5v = (k + 5 <= last) ? 1.f : 0.f;
        float m6v = (k + 6 <= last) ? 1.f : 0.f;
        sx += f0.x + m1v * f1.x + m2v * f2.x + m3v * f3.x + m4v * f4.x + m5v * f5.x + m6v * f6.x;
        sy += f0.y + m1v * f1.y + m2v * f2.y + m3v * f3.y + m4v * f4.y + m5v * f5.y + m6v * f6.y;
    }
    ushort2 su = hp[(size_t)n * 16 + cp];
    float2 sf = __half22float2(*(const __half2*)&su);
    float dn = dinv[n];
    int c0 = cp * 2, c1 = c0 + 1;
    float r0 = (sx + sf.x) * dn + b2[c0];
    float r1 = (sy + sf.y) * dn + b2[c1];
    r0 = (r0 - m2[c0]) * rsqrtf(v2[c0] + EPS) * g2[c0] + be2[c0];
    r1 = (r1 - m2[c1]) * rsqrtf(v2[c1] + EPS) * g2[c1] + be2[c1];
    r0 = fmaxf(r0, 0.f);
    r1 = fmaxf(r1, 0.f);
    float p0 = r0 * Wl[c0 * 2 + 0] + r1 * Wl[c1 * 2 + 0];
    float p1 = r0 * Wl[c0 * 2 + 1] + r1 * Wl[c1 * 2 + 1];
    #pragma unroll
    for (int off = 8; off > 0; off >>= 1) {
        p0 += __shfl_xor(p0, off);
        p1 += __shfl_xor(p1, off);
    }
    if (cp == 0) {
        *(float2*)&out[(size_t)n * NCLS] = make_float2(p0 + bl[0], p1 + bl[1]);
    }
}

extern "C" void kernel_launch(void* const* d_in, const int* in_sizes, int n_in,
                              void* d_out, int out_size, void* d_ws, size_t ws_size,
                              hipStream_t stream) {
    const float* x   = (const float*)d_in[0];
    const int*   ei  = (const int*)d_in[1];
    const int*   src = ei;
    const int*   dst = ei + N_EDGES;
    const float* W1  = (const float*)d_in[2];
    const float* b1  = (const float*)d_in[3];
    const float* g1  = (const float*)d_in[4];
    const float* be1 = (const float*)d_in[5];
    const float* m1  = (const float*)d_in[6];
    const float* v1  = (const float*)d_in[7];
    const float* W2  = (const float*)d_in[8];
    const float* b2  = (const float*)d_in[9];
    const float* g2  = (const float*)d_in[10];
    const float* be2 = (const float*)d_in[11];
    const float* m2  = (const float*)d_in[12];
    const float* v2  = (const float*)d_in[13];
    const float* Wl  = (const float*)d_in[14];
    const float* bl  = (const float*)d_in[15];
    float* out = (float*)d_out;

    char* p = (char*)d_ws;
    int*   bucket_count = (int*)p;  p += 1600;                     // NBK ints (+pad)
    int*   cursor       = (int*)p;  p += 1600;                     // NBK ints
    int*   bucket_base  = (int*)p;  p += 1600;                     // NBK+1 ints
    int*   offs         = (int*)p;  p += 400016;                   // N+1 ints
    float* dinv         = (float*)p; p += 400000;                  // N floats
    int*   packed       = (int*)p;  p += (size_t)N_EDGES * 4;      // E ints
    int*   csr          = (int*)p;  p += (size_t)N_EDGES * 4;      // E ints
    unsigned short* h1q = (unsigned short*)p; p += (size_t)N_NODES * H1 * 2;   // fp16 [4][N][16], dinv-scaled
    unsigned short* out1= (unsigned short*)p; p += (size_t)N_NODES * H1 * 2;   // fp16 [N][64]
    unsigned short* h2s = (unsigned short*)p; p += (size_t)N_NODES * H2C * 2;  // fp16 [N][32], dinv-scaled

    hipMemsetAsync(bucket_count, 0, 3200, stream);   // bucket_count + cursor

    k_bin_count<<<512, 256, 0, stream>>>(dst, bucket_count);
    k_bucket_scan<<<1, 512, 0, stream>>>(bucket_count, bucket_base);
    k_bin_scatter<<<(N_EDGES + SCHUNK - 1) / SCHUNK, 256, 0, stream>>>(src, dst, bucket_base, cursor, packed);
    k_csr_build<<<NBK, 256, 0, stream>>>(packed, bucket_base, csr, offs, dinv);
    k_gemm1<<<(N_NODES + 63) / 64, 256, 0, stream>>>(x, W1, dinv, h1q);
    k_agg1<<<4 * BPP, 256, 0, stream>>>(h1q, dinv, offs, csr, b1, g1, be1, m1, v1, out1);
    k_gemm2<<<(N_NODES * 32) / 256, 256, 0, stream>>>(out1, W2, dinv, h2s);
    k_agg2<<<(N_NODES * 16) / 256, 256, 0, stream>>>(h2s, dinv, offs, csr, b2, g2, be2, m2, v2, Wl, bl, out);
}

// Round 9
// 285.821 us; speedup vs baseline: 1.1601x; 1.1601x over previous
//
#include <hip/hip_runtime.h>
#include <hip/hip_fp16.h>

#define N_NODES 100000
#define N_EDGES 3200000
#define F_IN 256
#define H1 64
#define H2C 32
#define NCLS 2
#define EPS 1e-5f

#define NBK 391            // ceil(100000/256) buckets of 256 dst nodes
#define BK_CAP 10240       // max edges per bucket (mean 8184, sd ~90; 11+ sigma margin)
#define SCHUNK 16384       // edges per k_bin_scatter block

// ---------------- pass 1: per-bucket histogram ----------------
__global__ __launch_bounds__(256) void k_bin_count(const int* __restrict__ dst,
                                                   int* __restrict__ bucket_count) {
    __shared__ int h[NBK];
    for (int i = threadIdx.x; i < NBK; i += 256) h[i] = 0;
    __syncthreads();
    int stride = gridDim.x * 256;
    for (int e = blockIdx.x * 256 + threadIdx.x; e < N_EDGES; e += stride)
        atomicAdd(&h[((unsigned)dst[e]) >> 8], 1);
    __syncthreads();
    for (int i = threadIdx.x; i < NBK; i += 256)
        if (h[i]) atomicAdd(&bucket_count[i], h[i]);
}

// ---------------- pass 2: scan bucket counts ----------------
__global__ void k_bucket_scan(const int* __restrict__ bucket_count,
                              int* __restrict__ bucket_base) {
    __shared__ int s[512];
    int t = threadIdx.x;
    int v = (t < NBK) ? bucket_count[t] : 0;
    s[t] = v;
    __syncthreads();
    for (int off = 1; off < 512; off <<= 1) {
        int x = (t >= off) ? s[t - off] : 0;
        __syncthreads();
        s[t] += x;
        __syncthreads();
    }
    if (t < NBK) bucket_base[t] = s[t] - v;   // exclusive
    if (t == 0) bucket_base[NBK] = N_EDGES;
}

// ---------------- pass 3: scatter edges into bucket-major packed records ----------------
// packed record: (dst & 255) << 24 | src
__global__ __launch_bounds__(256) void k_bin_scatter(const int* __restrict__ src,
                                                     const int* __restrict__ dst,
                                                     const int* __restrict__ bucket_base,
                                                     int* __restrict__ cursor,
                                                     int* __restrict__ packed) {
    __shared__ int h[NBK];     // local hist, then local cursor
    __shared__ int base[NBK];  // global run base for this block
    int t = threadIdx.x;
    int e0 = blockIdx.x * SCHUNK;
    int e1 = e0 + SCHUNK; if (e1 > N_EDGES) e1 = N_EDGES;
    for (int i = t; i < NBK; i += 256) h[i] = 0;
    __syncthreads();
    for (int e = e0 + t; e < e1; e += 256)
        atomicAdd(&h[((unsigned)dst[e]) >> 8], 1);
    __syncthreads();
    for (int i = t; i < NBK; i += 256) {
        int c = h[i];
        base[i] = c ? (bucket_base[i] + atomicAdd(&cursor[i], c)) : 0;
        h[i] = 0;
    }
    __syncthreads();
    for (int e = e0 + t; e < e1; e += 256) {
        int d = dst[e];
        int b = ((unsigned)d) >> 8;
        int pos = base[b] + atomicAdd(&h[b], 1);
        packed[pos] = ((d & 255) << 24) | src[e];
    }
}

// ---------------- pass 4: per-bucket CSR build (LDS) + offs + dinv ----------------
__global__ __launch_bounds__(256) void k_csr_build(const int* __restrict__ packed,
                                                   const int* __restrict__ bucket_base,
                                                   int* __restrict__ csr,
                                                   int* __restrict__ offs_g,
                                                   float* __restrict__ dinv) {
    __shared__ int hist[256];
    __shared__ int offs[257];
    __shared__ int csr_l[BK_CAP];
    int t = threadIdx.x;
    int b = blockIdx.x;
    int node0 = b << 8;
    int nn = N_NODES - node0; if (nn > 256) nn = 256;
    int ebase = bucket_base[b];
    int ecnt = bucket_base[b + 1] - ebase;
    if (ecnt > BK_CAP) ecnt = BK_CAP;   // never triggers for this input; LDS safety

    hist[t] = 0;
    __syncthreads();
    for (int i = t; i < ecnt; i += 256)
        atomicAdd(&hist[((unsigned)packed[ebase + i]) >> 24], 1);
    __syncthreads();
    int d = hist[t];
    offs[t] = d;
    __syncthreads();
    for (int off = 1; off < 256; off <<= 1) {
        int x = (t >= off) ? offs[t - off] : 0;
        __syncthreads();
        offs[t] += x;
        __syncthreads();
    }
    int incl = offs[t];
    int excl = incl - d;
    __syncthreads();
    offs[t] = excl;
    if (t == 255) offs[256] = incl;   // == ecnt
    hist[t] = 0;                      // reuse as per-node cursor
    __syncthreads();
    for (int i = t; i < ecnt; i += 256) {
        int p = packed[ebase + i];
        int ld = ((unsigned)p) >> 24;
        int pos = offs[ld] + atomicAdd(&hist[ld], 1);
        csr_l[pos] = p & 0xFFFFFF;
    }
    __syncthreads();
    for (int i = t; i < ecnt; i += 256)
        csr[ebase + i] = csr_l[i];
    if (t < nn) {
        offs_g[node0 + t] = ebase + excl;
        dinv[node0 + t] = rsqrtf((float)d + 1.0f);
    }
    if (b == NBK - 1 && t == 0) offs_g[N_NODES] = N_EDGES;
}

// ---------------- GEMM1: h1s = fp16((x @ W1) * dinv[n])  [N,256]@[256,64], flat [N][64] ----------------
__global__ __launch_bounds__(256) void k_gemm1(const float* __restrict__ x,
                                               const float* __restrict__ W1,
                                               const float* __restrict__ dinv,
                                               unsigned short* __restrict__ h1s) {
    __shared__ float xt[32][64];   // [k][node]
    __shared__ float wt[32][64];   // [k][col]
    int t = threadIdx.x;
    int nodeBase = blockIdx.x * 64;
    int ng = t >> 4;        // 0..15 -> node group of 4
    int jg = t & 15;        // 0..15 -> col group of 4
    int ldn = t & 63;       // node for x staging
    int kq  = t >> 6;       // 0..3  -> k-octet for x staging
    int wcol = (t & 15) * 4;
    int kw  = t >> 4;       // 0..15 -> k row for W staging
    float acc[4][4] = {};
    for (int kc = 0; kc < F_IN; kc += 32) {
        int gn = nodeBase + ldn; if (gn >= N_NODES) gn = N_NODES - 1;
        const float* xr = x + (size_t)gn * F_IN + kc + kq * 8;
        float4 a0 = *(const float4*)xr;
        float4 a1 = *(const float4*)(xr + 4);
        int kb = kq * 8;
        xt[kb + 0][ldn] = a0.x; xt[kb + 1][ldn] = a0.y;
        xt[kb + 2][ldn] = a0.z; xt[kb + 3][ldn] = a0.w;
        xt[kb + 4][ldn] = a1.x; xt[kb + 5][ldn] = a1.y;
        xt[kb + 6][ldn] = a1.z; xt[kb + 7][ldn] = a1.w;
        const float* wr = W1 + (size_t)(kc + kw) * H1 + wcol;
        float4 b0 = *(const float4*)wr;
        float4 b1 = *(const float4*)(wr + 16 * H1);
        *(float4*)&wt[kw][wcol] = b0;
        *(float4*)&wt[kw + 16][wcol] = b1;
        __syncthreads();
        #pragma unroll
        for (int k = 0; k < 32; k++) {
            float4 av = *(const float4*)&xt[k][ng * 4];
            float4 bv = *(const float4*)&wt[k][jg * 4];
            acc[0][0] += av.x * bv.x; acc[0][1] += av.x * bv.y; acc[0][2] += av.x * bv.z; acc[0][3] += av.x * bv.w;
            acc[1][0] += av.y * bv.x; acc[1][1] += av.y * bv.y; acc[1][2] += av.y * bv.z; acc[1][3] += av.y * bv.w;
            acc[2][0] += av.z * bv.x; acc[2][1] += av.z * bv.y; acc[2][2] += av.z * bv.z; acc[2][3] += av.z * bv.w;
            acc[3][0] += av.w * bv.x; acc[3][1] += av.w * bv.y; acc[3][2] += av.w * bv.z; acc[3][3] += av.w * bv.w;
        }
        __syncthreads();
    }
    #pragma unroll
    for (int i = 0; i < 4; i++) {
        int n = nodeBase + ng * 4 + i;
        if (n < N_NODES) {
            float dn = dinv[n];
            ushort4 o;
            o.x = __half_as_ushort(__float2half(acc[i][0] * dn));
            o.y = __half_as_ushort(__float2half(acc[i][1] * dn));
            o.z = __half_as_ushort(__float2half(acc[i][2] * dn));
            o.w = __half_as_ushort(__float2half(acc[i][3] * dn));
            *(ushort4*)&h1s[(size_t)n * H1 + jg * 4] = o;
        }
    }
}

// ---- fused agg1 + BN1 + ReLU + GEMM2 + dinv-scale: 32 lanes/node, 2 ch/lane, 16-unroll ----
// writes h2s[n][j] = fp16(dinv[n] * sum_c relu(bn(agg1[n][c])) * W2[c][j])
__global__ __launch_bounds__(256) void k_agg1f(const unsigned short* __restrict__ h1s,
                                               const float* __restrict__ dinv,
                                               const int* __restrict__ offs,
                                               const int* __restrict__ csr,
                                               const float* __restrict__ b1,
                                               const float* __restrict__ g1,
                                               const float* __restrict__ be1,
                                               const float* __restrict__ m1,
                                               const float* __restrict__ v1,
                                               const float* __restrict__ W2,
                                               unsigned short* __restrict__ h2s) {
    __shared__ float w2[H1 * H2C];   // natural layout [c][j]
    __shared__ float rows[8][64];
    int t = threadIdx.x;
    for (int i = t; i < H1 * H2C; i += 256) w2[i] = W2[i];
    __syncthreads();

    int slot = t >> 5;           // 0..7 node slot within block
    int cp = t & 31;             // channel pair: channels 2cp, 2cp+1
    int n = blockIdx.x * 8 + slot;          // grid is exact: 12500*8 = 100000
    const ushort2* hp = (const ushort2*)h1s;   // [N][32]
    float sx = 0.f, sy = 0.f;
    int k = offs[n], kend = offs[n + 1];
    for (; k + 15 < kend; k += 16) {         // 16 gathers in flight
        int s0 = csr[k],      s1 = csr[k + 1],  s2 = csr[k + 2],  s3 = csr[k + 3];
        int s4 = csr[k + 4],  s5 = csr[k + 5],  s6 = csr[k + 6],  s7 = csr[k + 7];
        int s8 = csr[k + 8],  s9 = csr[k + 9],  sa = csr[k + 10], sb = csr[k + 11];
        int sc = csr[k + 12], sd = csr[k + 13], se = csr[k + 14], sf = csr[k + 15];
        ushort2 u0 = hp[(size_t)s0 * 32 + cp], u1 = hp[(size_t)s1 * 32 + cp];
        ushort2 u2 = hp[(size_t)s2 * 32 + cp], u3 = hp[(size_t)s3 * 32 + cp];
        ushort2 u4 = hp[(size_t)s4 * 32 + cp], u5 = hp[(size_t)s5 * 32 + cp];
        ushort2 u6 = hp[(size_t)s6 * 32 + cp], u7 = hp[(size_t)s7 * 32 + cp];
        ushort2 u8 = hp[(size_t)s8 * 32 + cp], u9 = hp[(size_t)s9 * 32 + cp];
        ushort2 ua = hp[(size_t)sa * 32 + cp], ub = hp[(size_t)sb * 32 + cp];
        ushort2 uc = hp[(size_t)sc * 32 + cp], ud = hp[(size_t)sd * 32 + cp];
        ushort2 ue = hp[(size_t)se * 32 + cp], uf = hp[(size_t)sf * 32 + cp];
        float2 f0 = __half22float2(*(const __half2*)&u0);
        float2 f1 = __half22float2(*(const __half2*)&u1);
        float2 f2 = __half22float2(*(const __half2*)&u2);
        float2 f3 = __half22float2(*(const __half2*)&u3);
        float2 f4 = __half22float2(*(const __half2*)&u4);
        float2 f5 = __half22float2(*(const __half2*)&u5);
        float2 f6 = __half22float2(*(const __half2*)&u6);
        float2 f7 = __half22float2(*(const __half2*)&u7);
        float2 f8 = __half22float2(*(const __half2*)&u8);
        float2 f9 = __half22float2(*(const __half2*)&u9);
        float2 fa = __half22float2(*(const __half2*)&ua);
        float2 fb = __half22float2(*(const __half2*)&ub);
        float2 fc = __half22float2(*(const __half2*)&uc);
        float2 fd = __half22float2(*(const __half2*)&ud);
        float2 fe = __half22float2(*(const __half2*)&ue);
        float2 ff = __half22float2(*(const __half2*)&uf);
        sx += ((f0.x + f1.x) + (f2.x + f3.x)) + ((f4.x + f5.x) + (f6.x + f7.x))
            + ((f8.x + f9.x) + (fa.x + fb.x)) + ((fc.x + fd.x) + (fe.x + ff.x));
        sy += ((f0.y + f1.y) + (f2.y + f3.y)) + ((f4.y + f5.y) + (f6.y + f7.y))
            + ((f8.y + f9.y) + (fa.y + fb.y)) + ((fc.y + fd.y) + (fe.y + ff.y));
    }
    for (; k + 7 < kend; k += 8) {
        int s0 = csr[k],     s1 = csr[k + 1], s2 = csr[k + 2], s3 = csr[k + 3];
        int s4 = csr[k + 4], s5 = csr[k + 5], s6 = csr[k + 6], s7 = csr[k + 7];
        ushort2 u0 = hp[(size_t)s0 * 32 + cp], u1 = hp[(size_t)s1 * 32 + cp];
        ushort2 u2 = hp[(size_t)s2 * 32 + cp], u3 = hp[(size_t)s3 * 32 + cp];
        ushort2 u4 = hp[(size_t)s4 * 32 + cp], u5 = hp[(size_t)s5 * 32 + cp];
        ushort2 u6 = hp[(size_t)s6 * 32 + cp], u7 = hp[(size_t)s7 * 32 + cp];
        float2 f0 = __half22float2(*(const __half2*)&u0);
        float2 f1 = __half22float2(*(const __half2*)&u1);
        float2 f2 = __half22float2(*(const __half2*)&u2);
        float2 f3 = __half22float2(*(const __half2*)&u3);
        float2 f4 = __half22float2(*(const __half2*)&u4);
        float2 f5 = __half22float2(*(const __half2*)&u5);
        float2 f6 = __half22float2(*(const __half2*)&u6);
        float2 f7 = __half22float2(*(const __half2*)&u7);
        sx += (f0.x + f1.x) + (f2.x + f3.x) + ((f4.x + f5.x) + (f6.x + f7.x));
        sy += (f0.y + f1.y) + (f2.y + f3.y) + ((f4.y + f5.y) + (f6.y + f7.y));
    }
    if (k < kend) {              // masked tail, <=7 remaining
        int last = kend - 1;
        int i1 = k + 1 <= last ? k + 1 : last;
        int i2 = k + 2 <= last ? k + 2 : last;
        int i3 = k + 3 <= last ? k + 3 : last;
        int i4 = k + 4 <= last ? k + 4 : last;
        int i5 = k + 5 <= last ? k + 5 : last;
        int i6 = k + 6 <= last ? k + 6 : last;
        int s0 = csr[k],  s1 = csr[i1], s2 = csr[i2], s3 = csr[i3];
        int s4 = csr[i4], s5 = csr[i5], s6 = csr[i6];
        ushort2 u0 = hp[(size_t)s0 * 32 + cp], u1 = hp[(size_t)s1 * 32 + cp];
        ushort2 u2 = hp[(size_t)s2 * 32 + cp], u3 = hp[(size_t)s3 * 32 + cp];
        ushort2 u4 = hp[(size_t)s4 * 32 + cp], u5 = hp[(size_t)s5 * 32 + cp];
        ushort2 u6 = hp[(size_t)s6 * 32 + cp];
        float2 f0 = __half22float2(*(const __half2*)&u0);
        float2 f1 = __half22float2(*(const __half2*)&u1);
        float2 f2 = __half22float2(*(const __half2*)&u2);
        float2 f3 = __half22float2(*(const __half2*)&u3);
        float2 f4 = __half22float2(*(const __half2*)&u4);
        float2 f5 = __half22float2(*(const __half2*)&u5);
        float2 f6 = __half22float2(*(const __half2*)&u6);
        float m1v = (k + 1 <= last) ? 1.f : 0.f;
        float m2v = (k + 2 <= last) ? 1.f : 0.f;
        float m3v = (k + 3 <= last) ? 1.f : 0.f;
        float m4v = (k + 4 <= last) ? 1.f : 0.f;
        float m5v = (k + 5 <= last) ? 1.f : 0.f;
        float m6v = (k + 6 <= last) ? 1.f : 0.f;
        sx += f0.x + m1v * f1.x + m2v * f2.x + m3v * f3.x + m4v * f4.x + m5v * f5.x + m6v * f6.x;
        sy += f0.y + m1v * f1.y + m2v * f2.y + m3v * f3.y + m4v * f4.y + m5v * f5.y + m6v * f6.y;
    }
    // self term (pre-scaled by dinv[n]) + BN1 + ReLU
    ushort2 su = hp[(size_t)n * 32 + cp];
    float2 sf2 = __half22float2(*(const __half2*)&su);
    float dn = dinv[n];
    int c0 = cp * 2, c1 = c0 + 1;
    float r0 = (sx + sf2.x) * dn + b1[c0];
    float r1 = (sy + sf2.y) * dn + b1[c1];
    r0 = (r0 - m1[c0]) * rsqrtf(v1[c0] + EPS) * g1[c0] + be1[c0];
    r1 = (r1 - m1[c1]) * rsqrtf(v1[c1] + EPS) * g1[c1] + be1[c1];
    rows[slot][c0] = fmaxf(r0, 0.f);
    rows[slot][c1] = fmaxf(r1, 0.f);
    __syncthreads();
    // in-block GEMM2: lane cp computes output channel j = cp of node `slot`
    const float4* rp = (const float4*)rows[slot];   // broadcast within half-wave
    float acc = 0.f;
    #pragma unroll
    for (int q = 0; q < 16; q++) {
        float4 rv = rp[q];
        int kb = q * 4;
        acc += rv.x * w2[(kb + 0) * H2C + cp] + rv.y * w2[(kb + 1) * H2C + cp]
             + rv.z * w2[(kb + 2) * H2C + cp] + rv.w * w2[(kb + 3) * H2C + cp];
    }
    h2s[(size_t)n * H2C + cp] = __half_as_ushort(__float2half(acc * dn));
}

// ---------------- agg2 + BN2 + ReLU + linear: 16 lanes/node, 2 ch/lane, 16-unroll ----------------
__global__ __launch_bounds__(256) void k_agg2(const unsigned short* __restrict__ h2s,
                                              const float* __restrict__ dinv,
                                              const int* __restrict__ offs,
                                              const int* __restrict__ csr,
                                              const float* __restrict__ b2,
                                              const float* __restrict__ g2,
                                              const float* __restrict__ be2,
                                              const float* __restrict__ m2,
                                              const float* __restrict__ v2,
                                              const float* __restrict__ Wl,
                                              const float* __restrict__ bl,
                                              float* __restrict__ out) {
    int gid = blockIdx.x * 256 + threadIdx.x;
    int n = gid >> 4;
    int cp = gid & 15;           // channel pair: channels 2cp, 2cp+1
    if (n >= N_NODES) return;
    const ushort2* hp = (const ushort2*)h2s;   // [N][16]
    float sx = 0.f, sy = 0.f;
    int k = offs[n], kend = offs[n + 1];
    for (; k + 15 < kend; k += 16) {
        int s0 = csr[k],      s1 = csr[k + 1],  s2 = csr[k + 2],  s3 = csr[k + 3];
        int s4 = csr[k + 4],  s5 = csr[k + 5],  s6 = csr[k + 6],  s7 = csr[k + 7];
        int s8 = csr[k + 8],  s9 = csr[k + 9],  sa = csr[k + 10], sb = csr[k + 11];
        int sc = csr[k + 12], sd = csr[k + 13], se = csr[k + 14], sf = csr[k + 15];
        ushort2 u0 = hp[(size_t)s0 * 16 + cp], u1 = hp[(size_t)s1 * 16 + cp];
        ushort2 u2 = hp[(size_t)s2 * 16 + cp], u3 = hp[(size_t)s3 * 16 + cp];
        ushort2 u4 = hp[(size_t)s4 * 16 + cp], u5 = hp[(size_t)s5 * 16 + cp];
        ushort2 u6 = hp[(size_t)s6 * 16 + cp], u7 = hp[(size_t)s7 * 16 + cp];
        ushort2 u8 = hp[(size_t)s8 * 16 + cp], u9 = hp[(size_t)s9 * 16 + cp];
        ushort2 ua = hp[(size_t)sa * 16 + cp], ub = hp[(size_t)sb * 16 + cp];
        ushort2 uc = hp[(size_t)sc * 16 + cp], ud = hp[(size_t)sd * 16 + cp];
        ushort2 ue = hp[(size_t)se * 16 + cp], uf = hp[(size_t)sf * 16 + cp];
        float2 f0 = __half22float2(*(const __half2*)&u0);
        float2 f1 = __half22float2(*(const __half2*)&u1);
        float2 f2 = __half22float2(*(const __half2*)&u2);
        float2 f3 = __half22float2(*(const __half2*)&u3);
        float2 f4 = __half22float2(*(const __half2*)&u4);
        float2 f5 = __half22float2(*(const __half2*)&u5);
        float2 f6 = __half22float2(*(const __half2*)&u6);
        float2 f7 = __half22float2(*(const __half2*)&u7);
        float2 f8 = __half22float2(*(const __half2*)&u8);
        float2 f9 = __half22float2(*(const __half2*)&u9);
        float2 fa = __half22float2(*(const __half2*)&ua);
        float2 fb = __half22float2(*(const __half2*)&ub);
        float2 fc = __half22float2(*(const __half2*)&uc);
        float2 fd = __half22float2(*(const __half2*)&ud);
        float2 fe = __half22float2(*(const __half2*)&ue);
        float2 ff = __half22float2(*(const __half2*)&uf);
        sx += ((f0.x + f1.x) + (f2.x + f3.x)) + ((f4.x + f5.x) + (f6.x + f7.x))
            + ((f8.x + f9.x) + (fa.x + fb.x)) + ((fc.x + fd.x) + (fe.x + ff.x));
        sy += ((f0.y + f1.y) + (f2.y + f3.y)) + ((f4.y + f5.y) + (f6.y + f7.y))
            + ((f8.y + f9.y) + (fa.y + fb.y)) + ((fc.y + fd.y) + (fe.y + ff.y));
    }
    for (; k + 7 < kend; k += 8) {
        int s0 = csr[k],     s1 = csr[k + 1], s2 = csr[k + 2], s3 = csr[k + 3];
        int s4 = csr[k + 4], s5 = csr[k + 5], s6 = csr[k + 6], s7 = csr[k + 7];
        ushort2 u0 = hp[(size_t)s0 * 16 + cp], u1 = hp[(size_t)s1 * 16 + cp];
        ushort2 u2 = hp[(size_t)s2 * 16 + cp], u3 = hp[(size_t)s3 * 16 + cp];
        ushort2 u4 = hp[(size_t)s4 * 16 + cp], u5 = hp[(size_t)s5 * 16 + cp];
        ushort2 u6 = hp[(size_t)s6 * 16 + cp], u7 = hp[(size_t)s7 * 16 + cp];
        float2 f0 = __half22float2(*(const __half2*)&u0);
        float2 f1 = __half22float2(*(const __half2*)&u1);
        float2 f2 = __half22float2(*(const __half2*)&u2);
        float2 f3 = __half22float2(*(const __half2*)&u3);
        float2 f4 = __half22float2(*(const __half2*)&u4);
        float2 f5 = __half22float2(*(const __half2*)&u5);
        float2 f6 = __half22float2(*(const __half2*)&u6);
        float2 f7 = __half22float2(*(const __half2*)&u7);
        sx += (f0.x + f1.x) + (f2.x + f3.x) + ((f4.x + f5.x) + (f6.x + f7.x));
        sy += (f0.y + f1.y) + (f2.y + f3.y) + ((f4.y + f5.y) + (f6.y + f7.y));
    }
    if (k < kend) {              // masked tail, <=7 remaining
        int last = kend - 1;
        int i1 = k + 1 <= last ? k + 1 : last;
        int i2 = k + 2 <= last ? k + 2 : last;
        int i3 = k + 3 <= last ? k + 3 : last;
        int i4 = k + 4 <= last ? k + 4 : last;
        int i5 = k + 5 <= last ? k + 5 : last;
        int i6 = k + 6 <= last ? k + 6 : last;
        int s0 = csr[k],  s1 = csr[i1], s2 = csr[i2], s3 = csr[i3];
        int s4 = csr[i4], s5 = csr[i5], s6 = csr[i6];
        ushort2 u0 = hp[(size_t)s0 * 16 + cp], u1 = hp[(size_t)s1 * 16 + cp];
        ushort2 u2 = hp[(size_t)s2 * 16 + cp], u3 = hp[(size_t)s3 * 16 + cp];
        ushort2 u4 = hp[(size_t)s4 * 16 + cp], u5 = hp[(size_t)s5 * 16 + cp];
        ushort2 u6 = hp[(size_t)s6 * 16 + cp];
        float2 f0 = __half22float2(*(const __half2*)&u0);
        float2 f1 = __half22float2(*(const __half2*)&u1);
        float2 f2 = __half22float2(*(const __half2*)&u2);
        float2 f3 = __half22float2(*(const __half2*)&u3);
        float2 f4 = __half22float2(*(const __half2*)&u4);
        float2 f5 = __half22float2(*(const __half2*)&u5);
        float2 f6 = __half22float2(*(const __half2*)&u6);
        float m1v = (k + 1 <= last) ? 1.f : 0.f;
        float m2v = (k + 2 <= last) ? 1.f : 0.f;
        float m3v = (k + 3 <= last) ? 1.f : 0.f;
        float m4v = (k + 4 <= last) ? 1.f : 0.f;
        float m5v = (k + 5 <= last) ? 1.f : 0.f;
        float m6v = (k + 6 <= last) ? 1.f : 0.f;
        sx += f0.x + m1v * f1.x + m2v * f2.x + m3v * f3.x + m4v * f4.x + m5v * f5.x + m6v * f6.x;
        sy += f0.y + m1v * f1.y + m2v * f2.y + m3v * f3.y + m4v * f4.y + m5v * f5.y + m6v * f6.y;
    }
    ushort2 su = hp[(size_t)n * 16 + cp];
    float2 sf2 = __half22float2(*(const __half2*)&su);
    float dn = dinv[n];
    int c0 = cp * 2, c1 = c0 + 1;
    float r0 = (sx + sf2.x) * dn + b2[c0];
    float r1 = (sy + sf2.y) * dn + b2[c1];
    r0 = (r0 - m2[c0]) * rsqrtf(v2[c0] + EPS) * g2[c0] + be2[c0];
    r1 = (r1 - m2[c1]) * rsqrtf(v2[c1] + EPS) * g2[c1] + be2[c1];
    r0 = fmaxf(r0, 0.f);
    r1 = fmaxf(r1, 0.f);
    float p0 = r0 * Wl[c0 * 2 + 0] + r1 * Wl[c1 * 2 + 0];
    float p1 = r0 * Wl[c0 * 2 + 1] + r1 * Wl[c1 * 2 + 1];
    #pragma unroll
    for (int off = 8; off > 0; off >>= 1) {
        p0 += __shfl_xor(p0, off);
        p1 += __shfl_xor(p1, off);
    }
    if (cp == 0) {
        *(float2*)&out[(size_t)n * NCLS] = make_float2(p0 + bl[0], p1 + bl[1]);
    }
}

extern "C" void kernel_launch(void* const* d_in, const int* in_sizes, int n_in,
                              void* d_out, int out_size, void* d_ws, size_t ws_size,
                              hipStream_t stream) {
    const float* x   = (const float*)d_in[0];
    const int*   ei  = (const int*)d_in[1];
    const int*   src = ei;
    const int*   dst = ei + N_EDGES;
    const float* W1  = (const float*)d_in[2];
    const float* b1  = (const float*)d_in[3];
    const float* g1  = (const float*)d_in[4];
    const float* be1 = (const float*)d_in[5];
    const float* m1  = (const float*)d_in[6];
    const float* v1  = (const float*)d_in[7];
    const float* W2  = (const float*)d_in[8];
    const float* b2  = (const float*)d_in[9];
    const float* g2  = (const float*)d_in[10];
    const float* be2 = (const float*)d_in[11];
    const float* m2  = (const float*)d_in[12];
    const float* v2  = (const float*)d_in[13];
    const float* Wl  = (const float*)d_in[14];
    const float* bl  = (const float*)d_in[15];
    float* out = (float*)d_out;

    char* p = (char*)d_ws;
    int*   bucket_count = (int*)p;  p += 1600;                     // NBK ints (+pad)
    int*   cursor       = (int*)p;  p += 1600;                     // NBK ints
    int*   bucket_base  = (int*)p;  p += 1600;                     // NBK+1 ints
    int*   offs         = (int*)p;  p += 400016;                   // N+1 ints
    float* dinv         = (float*)p; p += 400000;                  // N floats
    int*   packed       = (int*)p;  p += (size_t)N_EDGES * 4;      // E ints
    int*   csr          = (int*)p;  p += (size_t)N_EDGES * 4;      // E ints
    unsigned short* h1s = (unsigned short*)p; p += (size_t)N_NODES * H1 * 2;   // fp16 [N][64], dinv-scaled
    unsigned short* h2s = (unsigned short*)p; p += (size_t)N_NODES * H2C * 2;  // fp16 [N][32], dinv-scaled

    hipMemsetAsync(bucket_count, 0, 3200, stream);   // bucket_count + cursor

    k_bin_count<<<512, 256, 0, stream>>>(dst, bucket_count);
    k_bucket_scan<<<1, 512, 0, stream>>>(bucket_count, bucket_base);
    k_bin_scatter<<<(N_EDGES + SCHUNK - 1) / SCHUNK, 256, 0, stream>>>(src, dst, bucket_base, cursor, packed);
    k_csr_build<<<NBK, 256, 0, stream>>>(packed, bucket_base, csr, offs, dinv);
    k_gemm1<<<(N_NODES + 63) / 64, 256, 0, stream>>>(x, W1, dinv, h1s);
    k_agg1f<<<N_NODES / 8, 256, 0, stream>>>(h1s, dinv, offs, csr, b1, g1, be1, m1, v1, W2, h2s);
    k_agg2<<<(N_NODES * 16) / 256, 256, 0, stream>>>(h2s, dinv, offs, csr, b2, g2, be2, m2, v2, Wl, bl, out);
}

// Round 10
// 266.655 us; speedup vs baseline: 1.2434x; 1.0719x over previous
//
#include <hip/hip_runtime.h>
#include <hip/hip_fp16.h>

#define N_NODES 100000
#define N_EDGES 3200000
#define F_IN 256
#define H1 64
#define H2C 32
#define NCLS 2
#define EPS 1e-5f

#define NBK 391            // ceil(100000/256) buckets of 256 dst nodes
#define BK_CAP 10240       // max edges per bucket (mean 8184, sd ~90; 11+ sigma margin)
#define SCHUNK 16384       // edges per k_bin_scatter block

#define KPAD 264           // xt row stride in halves (256 + 8)
#define WPAD 40            // wtc row stride in halves (32 + 8)

typedef _Float16 f16x8 __attribute__((ext_vector_type(8)));
typedef float f32x4 __attribute__((ext_vector_type(4)));

// ---------------- pass 1: per-bucket histogram ----------------
__global__ __launch_bounds__(256) void k_bin_count(const int* __restrict__ dst,
                                                   int* __restrict__ bucket_count) {
    __shared__ int h[NBK];
    for (int i = threadIdx.x; i < NBK; i += 256) h[i] = 0;
    __syncthreads();
    int stride = gridDim.x * 256;
    for (int e = blockIdx.x * 256 + threadIdx.x; e < N_EDGES; e += stride)
        atomicAdd(&h[((unsigned)dst[e]) >> 8], 1);
    __syncthreads();
    for (int i = threadIdx.x; i < NBK; i += 256)
        if (h[i]) atomicAdd(&bucket_count[i], h[i]);
}

// ---------------- pass 2: scan bucket counts ----------------
__global__ void k_bucket_scan(const int* __restrict__ bucket_count,
                              int* __restrict__ bucket_base) {
    __shared__ int s[512];
    int t = threadIdx.x;
    int v = (t < NBK) ? bucket_count[t] : 0;
    s[t] = v;
    __syncthreads();
    for (int off = 1; off < 512; off <<= 1) {
        int x = (t >= off) ? s[t - off] : 0;
        __syncthreads();
        s[t] += x;
        __syncthreads();
    }
    if (t < NBK) bucket_base[t] = s[t] - v;   // exclusive
    if (t == 0) bucket_base[NBK] = N_EDGES;
}

// ---------------- pass 3: scatter edges into bucket-major packed records ----------------
// packed record: (dst & 255) << 24 | src
__global__ __launch_bounds__(256) void k_bin_scatter(const int* __restrict__ src,
                                                     const int* __restrict__ dst,
                                                     const int* __restrict__ bucket_base,
                                                     int* __restrict__ cursor,
                                                     int* __restrict__ packed) {
    __shared__ int h[NBK];     // local hist, then local cursor
    __shared__ int base[NBK];  // global run base for this block
    int t = threadIdx.x;
    int e0 = blockIdx.x * SCHUNK;
    int e1 = e0 + SCHUNK; if (e1 > N_EDGES) e1 = N_EDGES;
    for (int i = t; i < NBK; i += 256) h[i] = 0;
    __syncthreads();
    for (int e = e0 + t; e < e1; e += 256)
        atomicAdd(&h[((unsigned)dst[e]) >> 8], 1);
    __syncthreads();
    for (int i = t; i < NBK; i += 256) {
        int c = h[i];
        base[i] = c ? (bucket_base[i] + atomicAdd(&cursor[i], c)) : 0;
        h[i] = 0;
    }
    __syncthreads();
    for (int e = e0 + t; e < e1; e += 256) {
        int d = dst[e];
        int b = ((unsigned)d) >> 8;
        int pos = base[b] + atomicAdd(&h[b], 1);
        packed[pos] = ((d & 255) << 24) | src[e];
    }
}

// ---------------- pass 4: per-bucket CSR build (LDS) + offs + dinv ----------------
__global__ __launch_bounds__(256) void k_csr_build(const int* __restrict__ packed,
                                                   const int* __restrict__ bucket_base,
                                                   int* __restrict__ csr,
                                                   int* __restrict__ offs_g,
                                                   float* __restrict__ dinv) {
    __shared__ int hist[256];
    __shared__ int offs[257];
    __shared__ int csr_l[BK_CAP];
    int t = threadIdx.x;
    int b = blockIdx.x;
    int node0 = b << 8;
    int nn = N_NODES - node0; if (nn > 256) nn = 256;
    int ebase = bucket_base[b];
    int ecnt = bucket_base[b + 1] - ebase;
    if (ecnt > BK_CAP) ecnt = BK_CAP;   // never triggers for this input; LDS safety

    hist[t] = 0;
    __syncthreads();
    for (int i = t; i < ecnt; i += 256)
        atomicAdd(&hist[((unsigned)packed[ebase + i]) >> 24], 1);
    __syncthreads();
    int d = hist[t];
    offs[t] = d;
    __syncthreads();
    for (int off = 1; off < 256; off <<= 1) {
        int x = (t >= off) ? offs[t - off] : 0;
        __syncthreads();
        offs[t] += x;
        __syncthreads();
    }
    int incl = offs[t];
    int excl = incl - d;
    __syncthreads();
    offs[t] = excl;
    if (t == 255) offs[256] = incl;   // == ecnt
    hist[t] = 0;                      // reuse as per-node cursor
    __syncthreads();
    for (int i = t; i < ecnt; i += 256) {
        int p = packed[ebase + i];
        int ld = ((unsigned)p) >> 24;
        int pos = offs[ld] + atomicAdd(&hist[ld], 1);
        csr_l[pos] = p & 0xFFFFFF;
    }
    __syncthreads();
    for (int i = t; i < ecnt; i += 256)
        csr[ebase + i] = csr_l[i];
    if (t < nn) {
        offs_g[node0 + t] = ebase + excl;
        dinv[node0 + t] = rsqrtf((float)d + 1.0f);
    }
    if (b == NBK - 1 && t == 0) offs_g[N_NODES] = N_EDGES;
}

// ---------------- GEMM1 via MFMA fp16: h1s = fp16((x @ W1) * dinv[n]) ----------------
// block = 256 thr = 4 waves; 64 nodes/block; wave w -> nodes [w*16, w*16+16), all 64 cols.
__global__ __launch_bounds__(256) void k_gemm1m(const float* __restrict__ x,
                                                const float* __restrict__ W1,
                                                const float* __restrict__ dinv,
                                                unsigned short* __restrict__ h1s) {
    __shared__ __align__(16) unsigned short xt[64 * KPAD];   // 33.8 KB fp16 [node][k]
    __shared__ __align__(16) unsigned short wtc[64 * WPAD];  // 5.1 KB fp16 [col][kk] per chunk
    int t = threadIdx.x;
    int lane = t & 63;
    int w = t >> 6;
    int nodeBase = blockIdx.x * 64;

    // stage x block: 64 nodes x 256 k, fp32 -> fp16, coalesced (wave = one node row)
    #pragma unroll
    for (int i = 0; i < 16; i++) {
        int f = i * 256 + t;          // float4 index in [0,4096)
        int node = f >> 6;
        int pos = f & 63;             // float4 slot within row
        int gn = nodeBase + node; if (gn >= N_NODES) gn = N_NODES - 1;
        float4 v = *(const float4*)(x + (size_t)gn * F_IN + pos * 4);
        ushort4 h;
        h.x = __half_as_ushort(__float2half(v.x));
        h.y = __half_as_ushort(__float2half(v.y));
        h.z = __half_as_ushort(__float2half(v.z));
        h.w = __half_as_ushort(__float2half(v.w));
        *(ushort4*)&xt[node * KPAD + pos * 4] = h;
    }
    f32x4 acc0 = {}, acc1 = {}, acc2 = {}, acc3 = {};
    __syncthreads();

    int am = lane & 15;          // A row / B col / D col selector
    int ag = lane >> 4;          // k-group
    for (int kc = 0; kc < 8; kc++) {
        // stage W chunk (32 k x 64 c) transposed into [col][kk]
        #pragma unroll
        for (int i = 0; i < 2; i++) {
            int f = i * 256 + t;           // [0,512)
            int kk = f >> 4;
            int c4 = (f & 15) * 4;
            float4 v = *(const float4*)(W1 + (size_t)(kc * 32 + kk) * H1 + c4);
            wtc[(c4 + 0) * WPAD + kk] = __half_as_ushort(__float2half(v.x));
            wtc[(c4 + 1) * WPAD + kk] = __half_as_ushort(__float2half(v.y));
            wtc[(c4 + 2) * WPAD + kk] = __half_as_ushort(__float2half(v.z));
            wtc[(c4 + 3) * WPAD + kk] = __half_as_ushort(__float2half(v.w));
        }
        __syncthreads();
        f16x8 a = *(const f16x8*)&xt[(w * 16 + am) * KPAD + kc * 32 + ag * 8];
        f16x8 b0 = *(const f16x8*)&wtc[(0 * 16 + am) * WPAD + ag * 8];
        f16x8 b1 = *(const f16x8*)&wtc[(1 * 16 + am) * WPAD + ag * 8];
        f16x8 b2 = *(const f16x8*)&wtc[(2 * 16 + am) * WPAD + ag * 8];
        f16x8 b3 = *(const f16x8*)&wtc[(3 * 16 + am) * WPAD + ag * 8];
        acc0 = __builtin_amdgcn_mfma_f32_16x16x32_f16(a, b0, acc0, 0, 0, 0);
        acc1 = __builtin_amdgcn_mfma_f32_16x16x32_f16(a, b1, acc1, 0, 0, 0);
        acc2 = __builtin_amdgcn_mfma_f32_16x16x32_f16(a, b2, acc2, 0, 0, 0);
        acc3 = __builtin_amdgcn_mfma_f32_16x16x32_f16(a, b3, acc3, 0, 0, 0);
        __syncthreads();
    }

    // epilogue: D[row][col], row = ag*4 + r (node within wave tile), col = jt*16 + am
    #pragma unroll
    for (int r = 0; r < 4; r++) {
        int node = nodeBase + w * 16 + ag * 4 + r;
        if (node < N_NODES) {
            float dn = dinv[node];
            unsigned short* orow = &h1s[(size_t)node * H1];
            orow[ 0 + am] = __half_as_ushort(__float2half(acc0[r] * dn));
            orow[16 + am] = __half_as_ushort(__float2half(acc1[r] * dn));
            orow[32 + am] = __half_as_ushort(__float2half(acc2[r] * dn));
            orow[48 + am] = __half_as_ushort(__float2half(acc3[r] * dn));
        }
    }
}

// ---- fused agg1 + BN1 + ReLU + GEMM2 + dinv-scale: 32 lanes/node, 2 ch/lane, 16-unroll ----
// writes h2s[n][j] = fp16(dinv[n] * sum_c relu(bn(agg1[n][c])) * W2[c][j])
__global__ __launch_bounds__(256) void k_agg1f(const unsigned short* __restrict__ h1s,
                                               const float* __restrict__ dinv,
                                               const int* __restrict__ offs,
                                               const int* __restrict__ csr,
                                               const float* __restrict__ b1,
                                               const float* __restrict__ g1,
                                               const float* __restrict__ be1,
                                               const float* __restrict__ m1,
                                               const float* __restrict__ v1,
                                               const float* __restrict__ W2,
                                               unsigned short* __restrict__ h2s) {
    __shared__ float w2[H1 * H2C];   // natural layout [c][j]
    __shared__ float rows[8][64];
    int t = threadIdx.x;
    for (int i = t; i < H1 * H2C; i += 256) w2[i] = W2[i];
    __syncthreads();

    int slot = t >> 5;           // 0..7 node slot within block
    int cp = t & 31;             // channel pair: channels 2cp, 2cp+1
    int n = blockIdx.x * 8 + slot;          // grid is exact: 12500*8 = 100000
    const ushort2* hp = (const ushort2*)h1s;   // [N][32]
    float sx = 0.f, sy = 0.f;
    int k = offs[n], kend = offs[n + 1];
    for (; k + 15 < kend; k += 16) {         // 16 gathers in flight
        int s0 = csr[k],      s1 = csr[k + 1],  s2 = csr[k + 2],  s3 = csr[k + 3];
        int s4 = csr[k + 4],  s5 = csr[k + 5],  s6 = csr[k + 6],  s7 = csr[k + 7];
        int s8 = csr[k + 8],  s9 = csr[k + 9],  sa = csr[k + 10], sb = csr[k + 11];
        int sc = csr[k + 12], sd = csr[k + 13], se = csr[k + 14], sf = csr[k + 15];
        ushort2 u0 = hp[(size_t)s0 * 32 + cp], u1 = hp[(size_t)s1 * 32 + cp];
        ushort2 u2 = hp[(size_t)s2 * 32 + cp], u3 = hp[(size_t)s3 * 32 + cp];
        ushort2 u4 = hp[(size_t)s4 * 32 + cp], u5 = hp[(size_t)s5 * 32 + cp];
        ushort2 u6 = hp[(size_t)s6 * 32 + cp], u7 = hp[(size_t)s7 * 32 + cp];
        ushort2 u8 = hp[(size_t)s8 * 32 + cp], u9 = hp[(size_t)s9 * 32 + cp];
        ushort2 ua = hp[(size_t)sa * 32 + cp], ub = hp[(size_t)sb * 32 + cp];
        ushort2 uc = hp[(size_t)sc * 32 + cp], ud = hp[(size_t)sd * 32 + cp];
        ushort2 ue = hp[(size_t)se * 32 + cp], uf = hp[(size_t)sf * 32 + cp];
        float2 f0 = __half22float2(*(const __half2*)&u0);
        float2 f1 = __half22float2(*(const __half2*)&u1);
        float2 f2 = __half22float2(*(const __half2*)&u2);
        float2 f3 = __half22float2(*(const __half2*)&u3);
        float2 f4 = __half22float2(*(const __half2*)&u4);
        float2 f5 = __half22float2(*(const __half2*)&u5);
        float2 f6 = __half22float2(*(const __half2*)&u6);
        float2 f7 = __half22float2(*(const __half2*)&u7);
        float2 f8 = __half22float2(*(const __half2*)&u8);
        float2 f9 = __half22float2(*(const __half2*)&u9);
        float2 fa = __half22float2(*(const __half2*)&ua);
        float2 fb = __half22float2(*(const __half2*)&ub);
        float2 fc = __half22float2(*(const __half2*)&uc);
        float2 fd = __half22float2(*(const __half2*)&ud);
        float2 fe = __half22float2(*(const __half2*)&ue);
        float2 ff = __half22float2(*(const __half2*)&uf);
        sx += ((f0.x + f1.x) + (f2.x + f3.x)) + ((f4.x + f5.x) + (f6.x + f7.x))
            + ((f8.x + f9.x) + (fa.x + fb.x)) + ((fc.x + fd.x) + (fe.x + ff.x));
        sy += ((f0.y + f1.y) + (f2.y + f3.y)) + ((f4.y + f5.y) + (f6.y + f7.y))
            + ((f8.y + f9.y) + (fa.y + fb.y)) + ((fc.y + fd.y) + (fe.y + ff.y));
    }
    for (; k + 7 < kend; k += 8) {
        int s0 = csr[k],     s1 = csr[k + 1], s2 = csr[k + 2], s3 = csr[k + 3];
        int s4 = csr[k + 4], s5 = csr[k + 5], s6 = csr[k + 6], s7 = csr[k + 7];
        ushort2 u0 = hp[(size_t)s0 * 32 + cp], u1 = hp[(size_t)s1 * 32 + cp];
        ushort2 u2 = hp[(size_t)s2 * 32 + cp], u3 = hp[(size_t)s3 * 32 + cp];
        ushort2 u4 = hp[(size_t)s4 * 32 + cp], u5 = hp[(size_t)s5 * 32 + cp];
        ushort2 u6 = hp[(size_t)s6 * 32 + cp], u7 = hp[(size_t)s7 * 32 + cp];
        float2 f0 = __half22float2(*(const __half2*)&u0);
        float2 f1 = __half22float2(*(const __half2*)&u1);
        float2 f2 = __half22float2(*(const __half2*)&u2);
        float2 f3 = __half22float2(*(const __half2*)&u3);
        float2 f4 = __half22float2(*(const __half2*)&u4);
        float2 f5 = __half22float2(*(const __half2*)&u5);
        float2 f6 = __half22float2(*(const __half2*)&u6);
        float2 f7 = __half22float2(*(const __half2*)&u7);
        sx += (f0.x + f1.x) + (f2.x + f3.x) + ((f4.x + f5.x) + (f6.x + f7.x));
        sy += (f0.y + f1.y) + (f2.y + f3.y) + ((f4.y + f5.y) + (f6.y + f7.y));
    }
    if (k < kend) {              // masked tail, <=7 remaining
        int last = kend - 1;
        int i1 = k + 1 <= last ? k + 1 : last;
        int i2 = k + 2 <= last ? k + 2 : last;
        int i3 = k + 3 <= last ? k + 3 : last;
        int i4 = k + 4 <= last ? k + 4 : last;
        int i5 = k + 5 <= last ? k + 5 : last;
        int i6 = k + 6 <= last ? k + 6 : last;
        int s0 = csr[k],  s1 = csr[i1], s2 = csr[i2], s3 = csr[i3];
        int s4 = csr[i4], s5 = csr[i5], s6 = csr[i6];
        ushort2 u0 = hp[(size_t)s0 * 32 + cp], u1 = hp[(size_t)s1 * 32 + cp];
        ushort2 u2 = hp[(size_t)s2 * 32 + cp], u3 = hp[(size_t)s3 * 32 + cp];
        ushort2 u4 = hp[(size_t)s4 * 32 + cp], u5 = hp[(size_t)s5 * 32 + cp];
        ushort2 u6 = hp[(size_t)s6 * 32 + cp];
        float2 f0 = __half22float2(*(const __half2*)&u0);
        float2 f1 = __half22float2(*(const __half2*)&u1);
        float2 f2 = __half22float2(*(const __half2*)&u2);
        float2 f3 = __half22float2(*(const __half2*)&u3);
        float2 f4 = __half22float2(*(const __half2*)&u4);
        float2 f5 = __half22float2(*(const __half2*)&u5);
        float2 f6 = __half22float2(*(const __half2*)&u6);
        float m1v = (k + 1 <= last) ? 1.f : 0.f;
        float m2v = (k + 2 <= last) ? 1.f : 0.f;
        float m3v = (k + 3 <= last) ? 1.f : 0.f;
        float m4v = (k + 4 <= last) ? 1.f : 0.f;
        float m5v = (k + 5 <= last) ? 1.f : 0.f;
        float m6v = (k + 6 <= last) ? 1.f : 0.f;
        sx += f0.x + m1v * f1.x + m2v * f2.x + m3v * f3.x + m4v * f4.x + m5v * f5.x + m6v * f6.x;
        sy += f0.y + m1v * f1.y + m2v * f2.y + m3v * f3.y + m4v * f4.y + m5v * f5.y + m6v * f6.y;
    }
    // self term (pre-scaled by dinv[n]) + BN1 + ReLU
    ushort2 su = hp[(size_t)n * 32 + cp];
    float2 sf2 = __half22float2(*(const __half2*)&su);
    float dn = dinv[n];
    int c0 = cp * 2, c1 = c0 + 1;
    float r0 = (sx + sf2.x) * dn + b1[c0];
    float r1 = (sy + sf2.y) * dn + b1[c1];
    r0 = (r0 - m1[c0]) * rsqrtf(v1[c0] + EPS) * g1[c0] + be1[c0];
    r1 = (r1 - m1[c1]) * rsqrtf(v1[c1] + EPS) * g1[c1] + be1[c1];
    rows[slot][c0] = fmaxf(r0, 0.f);
    rows[slot][c1] = fmaxf(r1, 0.f);
    __syncthreads();
    // in-block GEMM2: lane cp computes output channel j = cp of node `slot`
    const float4* rp = (const float4*)rows[slot];   // broadcast within half-wave
    float acc = 0.f;
    #pragma unroll
    for (int q = 0; q < 16; q++) {
        float4 rv = rp[q];
        int kb = q * 4;
        acc += rv.x * w2[(kb + 0) * H2C + cp] + rv.y * w2[(kb + 1) * H2C + cp]
             + rv.z * w2[(kb + 2) * H2C + cp] + rv.w * w2[(kb + 3) * H2C + cp];
    }
    h2s[(size_t)n * H2C + cp] = __half_as_ushort(__float2half(acc * dn));
}

// ---------------- agg2 + BN2 + ReLU + linear: 16 lanes/node, 2 ch/lane, 16-unroll ----------------
__global__ __launch_bounds__(256) void k_agg2(const unsigned short* __restrict__ h2s,
                                              const float* __restrict__ dinv,
                                              const int* __restrict__ offs,
                                              const int* __restrict__ csr,
                                              const float* __restrict__ b2,
                                              const float* __restrict__ g2,
                                              const float* __restrict__ be2,
                                              const float* __restrict__ m2,
                                              const float* __restrict__ v2,
                                              const float* __restrict__ Wl,
                                              const float* __restrict__ bl,
                                              float* __restrict__ out) {
    int gid = blockIdx.x * 256 + threadIdx.x;
    int n = gid >> 4;
    int cp = gid & 15;           // channel pair: channels 2cp, 2cp+1
    if (n >= N_NODES) return;
    const ushort2* hp = (const ushort2*)h2s;   // [N][16]
    float sx = 0.f, sy = 0.f;
    int k = offs[n], kend = offs[n + 1];
    for (; k + 15 < kend; k += 16) {
        int s0 = csr[k],      s1 = csr[k + 1],  s2 = csr[k + 2],  s3 = csr[k + 3];
        int s4 = csr[k + 4],  s5 = csr[k + 5],  s6 = csr[k + 6],  s7 = csr[k + 7];
        int s8 = csr[k + 8],  s9 = csr[k + 9],  sa = csr[k + 10], sb = csr[k + 11];
        int sc = csr[k + 12], sd = csr[k + 13], se = csr[k + 14], sf = csr[k + 15];
        ushort2 u0 = hp[(size_t)s0 * 16 + cp], u1 = hp[(size_t)s1 * 16 + cp];
        ushort2 u2 = hp[(size_t)s2 * 16 + cp], u3 = hp[(size_t)s3 * 16 + cp];
        ushort2 u4 = hp[(size_t)s4 * 16 + cp], u5 = hp[(size_t)s5 * 16 + cp];
        ushort2 u6 = hp[(size_t)s6 * 16 + cp], u7 = hp[(size_t)s7 * 16 + cp];
        ushort2 u8 = hp[(size_t)s8 * 16 + cp], u9 = hp[(size_t)s9 * 16 + cp];
        ushort2 ua = hp[(size_t)sa * 16 + cp], ub = hp[(size_t)sb * 16 + cp];
        ushort2 uc = hp[(size_t)sc * 16 + cp], ud = hp[(size_t)sd * 16 + cp];
        ushort2 ue = hp[(size_t)se * 16 + cp], uf = hp[(size_t)sf * 16 + cp];
        float2 f0 = __half22float2(*(const __half2*)&u0);
        float2 f1 = __half22float2(*(const __half2*)&u1);
        float2 f2 = __half22float2(*(const __half2*)&u2);
        float2 f3 = __half22float2(*(const __half2*)&u3);
        float2 f4 = __half22float2(*(const __half2*)&u4);
        float2 f5 = __half22float2(*(const __half2*)&u5);
        float2 f6 = __half22float2(*(const __half2*)&u6);
        float2 f7 = __half22float2(*(const __half2*)&u7);
        float2 f8 = __half22float2(*(const __half2*)&u8);
        float2 f9 = __half22float2(*(const __half2*)&u9);
        float2 fa = __half22float2(*(const __half2*)&ua);
        float2 fb = __half22float2(*(const __half2*)&ub);
        float2 fc = __half22float2(*(const __half2*)&uc);
        float2 fd = __half22float2(*(const __half2*)&ud);
        float2 fe = __half22float2(*(const __half2*)&ue);
        float2 ff = __half22float2(*(const __half2*)&uf);
        sx += ((f0.x + f1.x) + (f2.x + f3.x)) + ((f4.x + f5.x) + (f6.x + f7.x))
            + ((f8.x + f9.x) + (fa.x + fb.x)) + ((fc.x + fd.x) + (fe.x + ff.x));
        sy += ((f0.y + f1.y) + (f2.y + f3.y)) + ((f4.y + f5.y) + (f6.y + f7.y))
            + ((f8.y + f9.y) + (fa.y + fb.y)) + ((fc.y + fd.y) + (fe.y + ff.y));
    }
    for (; k + 7 < kend; k += 8) {
        int s0 = csr[k],     s1 = csr[k + 1], s2 = csr[k + 2], s3 = csr[k + 3];
        int s4 = csr[k + 4], s5 = csr[k + 5], s6 = csr[k + 6], s7 = csr[k + 7];
        ushort2 u0 = hp[(size_t)s0 * 16 + cp], u1 = hp[(size_t)s1 * 16 + cp];
        ushort2 u2 = hp[(size_t)s2 * 16 + cp], u3 = hp[(size_t)s3 * 16 + cp];
        ushort2 u4 = hp[(size_t)s4 * 16 + cp], u5 = hp[(size_t)s5 * 16 + cp];
        ushort2 u6 = hp[(size_t)s6 * 16 + cp], u7 = hp[(size_t)s7 * 16 + cp];
        float2 f0 = __half22float2(*(const __half2*)&u0);
        float2 f1 = __half22float2(*(const __half2*)&u1);
        float2 f2 = __half22float2(*(const __half2*)&u2);
        float2 f3 = __half22float2(*(const __half2*)&u3);
        float2 f4 = __half22float2(*(const __half2*)&u4);
        float2 f5 = __half22float2(*(const __half2*)&u5);
        float2 f6 = __half22float2(*(const __half2*)&u6);
        float2 f7 = __half22float2(*(const __half2*)&u7);
        sx += (f0.x + f1.x) + (f2.x + f3.x) + ((f4.x + f5.x) + (f6.x + f7.x));
        sy += (f0.y + f1.y) + (f2.y + f3.y) + ((f4.y + f5.y) + (f6.y + f7.y));
    }
    if (k < kend) {              // masked tail, <=7 remaining
        int last = kend - 1;
        int i1 = k + 1 <= last ? k + 1 : last;
        int i2 = k + 2 <= last ? k + 2 : last;
        int i3 = k + 3 <= last ? k + 3 : last;
        int i4 = k + 4 <= last ? k + 4 : last;
        int i5 = k + 5 <= last ? k + 5 : last;
        int i6 = k + 6 <= last ? k + 6 : last;
        int s0 = csr[k],  s1 = csr[i1], s2 = csr[i2], s3 = csr[i3];
        int s4 = csr[i4], s5 = csr[i5], s6 = csr[i6];
        ushort2 u0 = hp[(size_t)s0 * 16 + cp], u1 = hp[(size_t)s1 * 16 + cp];
        ushort2 u2 = hp[(size_t)s2 * 16 + cp], u3 = hp[(size_t)s3 * 16 + cp];
        ushort2 u4 = hp[(size_t)s4 * 16 + cp], u5 = hp[(size_t)s5 * 16 + cp];
        ushort2 u6 = hp[(size_t)s6 * 16 + cp];
        float2 f0 = __half22float2(*(const __half2*)&u0);
        float2 f1 = __half22float2(*(const __half2*)&u1);
        float2 f2 = __half22float2(*(const __half2*)&u2);
        float2 f3 = __half22float2(*(const __half2*)&u3);
        float2 f4 = __half22float2(*(const __half2*)&u4);
        float2 f5 = __half22float2(*(const __half2*)&u5);
        float2 f6 = __half22float2(*(const __half2*)&u6);
        float m1v = (k + 1 <= last) ? 1.f : 0.f;
        float m2v = (k + 2 <= last) ? 1.f : 0.f;
        float m3v = (k + 3 <= last) ? 1.f : 0.f;
        float m4v = (k + 4 <= last) ? 1.f : 0.f;
        float m5v = (k + 5 <= last) ? 1.f : 0.f;
        float m6v = (k + 6 <= last) ? 1.f : 0.f;
        sx += f0.x + m1v * f1.x + m2v * f2.x + m3v * f3.x + m4v * f4.x + m5v * f5.x + m6v * f6.x;
        sy += f0.y + m1v * f1.y + m2v * f2.y + m3v * f3.y + m4v * f4.y + m5v * f5.y + m6v * f6.y;
    }
    ushort2 su = hp[(size_t)n * 16 + cp];
    float2 sf2 = __half22float2(*(const __half2*)&su);
    float dn = dinv[n];
    int c0 = cp * 2, c1 = c0 + 1;
    float r0 = (sx + sf2.x) * dn + b2[c0];
    float r1 = (sy + sf2.y) * dn + b2[c1];
    r0 = (r0 - m2[c0]) * rsqrtf(v2[c0] + EPS) * g2[c0] + be2[c0];
    r1 = (r1 - m2[c1]) * rsqrtf(v2[c1] + EPS) * g2[c1] + be2[c1];
    r0 = fmaxf(r0, 0.f);
    r1 = fmaxf(r1, 0.f);
    float p0 = r0 * Wl[c0 * 2 + 0] + r1 * Wl[c1 * 2 + 0];
    float p1 = r0 * Wl[c0 * 2 + 1] + r1 * Wl[c1 * 2 + 1];
    #pragma unroll
    for (int off = 8; off > 0; off >>= 1) {
        p0 += __shfl_xor(p0, off);
        p1 += __shfl_xor(p1, off);
    }
    if (cp == 0) {
        *(float2*)&out[(size_t)n * NCLS] = make_float2(p0 + bl[0], p1 + bl[1]);
    }
}

extern "C" void kernel_launch(void* const* d_in, const int* in_sizes, int n_in,
                              void* d_out, int out_size, void* d_ws, size_t ws_size,
                              hipStream_t stream) {
    const float* x   = (const float*)d_in[0];
    const int*   ei  = (const int*)d_in[1];
    const int*   src = ei;
    const int*   dst = ei + N_EDGES;
    const float* W1  = (const float*)d_in[2];
    const float* b1  = (const float*)d_in[3];
    const float* g1  = (const float*)d_in[4];
    const float* be1 = (const float*)d_in[5];
    const float* m1  = (const float*)d_in[6];
    const float* v1  = (const float*)d_in[7];
    const float* W2  = (const float*)d_in[8];
    const float* b2  = (const float*)d_in[9];
    const float* g2  = (const float*)d_in[10];
    const float* be2 = (const float*)d_in[11];
    const float* m2  = (const float*)d_in[12];
    const float* v2  = (const float*)d_in[13];
    const float* Wl  = (const float*)d_in[14];
    const float* bl  = (const float*)d_in[15];
    float* out = (float*)d_out;

    char* p = (char*)d_ws;
    int*   bucket_count = (int*)p;  p += 1600;                     // NBK ints (+pad)
    int*   cursor       = (int*)p;  p += 1600;                     // NBK ints
    int*   bucket_base  = (int*)p;  p += 1600;                     // NBK+1 ints
    int*   offs         = (int*)p;  p += 400016;                   // N+1 ints
    float* dinv         = (float*)p; p += 400000;                  // N floats
    int*   packed       = (int*)p;  p += (size_t)N_EDGES * 4;      // E ints
    int*   csr          = (int*)p;  p += (size_t)N_EDGES * 4;      // E ints
    unsigned short* h1s = (unsigned short*)p; p += (size_t)N_NODES * H1 * 2;   // fp16 [N][64], dinv-scaled
    unsigned short* h2s = (unsigned short*)p; p += (size_t)N_NODES * H2C * 2;  // fp16 [N][32], dinv-scaled

    hipMemsetAsync(bucket_count, 0, 3200, stream);   // bucket_count + cursor

    k_bin_count<<<512, 256, 0, stream>>>(dst, bucket_count);
    k_bucket_scan<<<1, 512, 0, stream>>>(bucket_count, bucket_base);
    k_bin_scatter<<<(N_EDGES + SCHUNK - 1) / SCHUNK, 256, 0, stream>>>(src, dst, bucket_base, cursor, packed);
    k_csr_build<<<NBK, 256, 0, stream>>>(packed, bucket_base, csr, offs, dinv);
    k_gemm1m<<<(N_NODES + 63) / 64, 256, 0, stream>>>(x, W1, dinv, h1s);
    k_agg1f<<<N_NODES / 8, 256, 0, stream>>>(h1s, dinv, offs, csr, b1, g1, be1, m1, v1, W2, h2s);
    k_agg2<<<(N_NODES * 16) / 256, 256, 0, stream>>>(h2s, dinv, offs, csr, b2, g2, be2, m2, v2, Wl, bl, out);
}

// Round 11
// 265.761 us; speedup vs baseline: 1.2476x; 1.0034x over previous
//
#include <hip/hip_runtime.h>
#include <hip/hip_fp16.h>

#define N_NODES 100000
#define N_EDGES 3200000
#define F_IN 256
#define H1 64
#define H2C 32
#define NCLS 2
#define EPS 1e-5f

#define NBK 391            // ceil(100000/256) buckets of 256 dst nodes
#define BK_CAP 10240       // max edges per bucket (mean 8184, sd ~90; 11+ sigma margin)
#define SCHUNK 16384       // edges per k_bin_scatter block

#define KPAD 264           // xt row stride in halves (256 + 8)
#define WPAD 40            // wtc row stride in halves (32 + 8)

typedef _Float16 f16x8 __attribute__((ext_vector_type(8)));
typedef float f32x4 __attribute__((ext_vector_type(4)));

// ---------------- pass 1: per-bucket histogram ----------------
__global__ __launch_bounds__(256) void k_bin_count(const int* __restrict__ dst,
                                                   int* __restrict__ bucket_count) {
    __shared__ int h[NBK];
    for (int i = threadIdx.x; i < NBK; i += 256) h[i] = 0;
    __syncthreads();
    int stride = gridDim.x * 256;
    for (int e = blockIdx.x * 256 + threadIdx.x; e < N_EDGES; e += stride)
        atomicAdd(&h[((unsigned)dst[e]) >> 8], 1);
    __syncthreads();
    for (int i = threadIdx.x; i < NBK; i += 256)
        if (h[i]) atomicAdd(&bucket_count[i], h[i]);
}

// ---------------- pass 2: scan bucket counts ----------------
__global__ void k_bucket_scan(const int* __restrict__ bucket_count,
                              int* __restrict__ bucket_base) {
    __shared__ int s[512];
    int t = threadIdx.x;
    int v = (t < NBK) ? bucket_count[t] : 0;
    s[t] = v;
    __syncthreads();
    for (int off = 1; off < 512; off <<= 1) {
        int x = (t >= off) ? s[t - off] : 0;
        __syncthreads();
        s[t] += x;
        __syncthreads();
    }
    if (t < NBK) bucket_base[t] = s[t] - v;   // exclusive
    if (t == 0) bucket_base[NBK] = N_EDGES;
}

// ---------------- pass 3: scatter edges into bucket-major packed records ----------------
// packed record: (dst & 255) << 24 | src
__global__ __launch_bounds__(256) void k_bin_scatter(const int* __restrict__ src,
                                                     const int* __restrict__ dst,
                                                     const int* __restrict__ bucket_base,
                                                     int* __restrict__ cursor,
                                                     int* __restrict__ packed) {
    __shared__ int h[NBK];     // local hist, then local cursor
    __shared__ int base[NBK];  // global run base for this block
    int t = threadIdx.x;
    int e0 = blockIdx.x * SCHUNK;
    int e1 = e0 + SCHUNK; if (e1 > N_EDGES) e1 = N_EDGES;
    for (int i = t; i < NBK; i += 256) h[i] = 0;
    __syncthreads();
    for (int e = e0 + t; e < e1; e += 256)
        atomicAdd(&h[((unsigned)dst[e]) >> 8], 1);
    __syncthreads();
    for (int i = t; i < NBK; i += 256) {
        int c = h[i];
        base[i] = c ? (bucket_base[i] + atomicAdd(&cursor[i], c)) : 0;
        h[i] = 0;
    }
    __syncthreads();
    for (int e = e0 + t; e < e1; e += 256) {
        int d = dst[e];
        int b = ((unsigned)d) >> 8;
        int pos = base[b] + atomicAdd(&h[b], 1);
        packed[pos] = ((d & 255) << 24) | src[e];
    }
}

// ---- pass 4: per-bucket CSR build, src-SLICE-SORTED per node (cache-blocked gather) ----
// composite histogram over (local_dst, slice=src>>15): csr lists come out slice-ordered.
__global__ __launch_bounds__(256) void k_csr_build(const int* __restrict__ packed,
                                                   const int* __restrict__ bucket_base,
                                                   int* __restrict__ csr,
                                                   int* __restrict__ offs_g,
                                                   float* __restrict__ dinv) {
    __shared__ int hist[1024];    // [node256][slice4] counts, then cursors
    __shared__ int nsum[256];
    __shared__ int csr_l[BK_CAP];
    int t = threadIdx.x;
    int b = blockIdx.x;
    int node0 = b << 8;
    int nn = N_NODES - node0; if (nn > 256) nn = 256;
    int ebase = bucket_base[b];
    int ecnt = bucket_base[b + 1] - ebase;
    if (ecnt > BK_CAP) ecnt = BK_CAP;   // never triggers for this input; LDS safety

    for (int i = t; i < 1024; i += 256) hist[i] = 0;
    __syncthreads();
    for (int i = t; i < ecnt; i += 256) {
        int p = packed[ebase + i];
        int ld = ((unsigned)p) >> 24;
        int sl = (p & 0xFFFFFF) >> 15;          // src slice 0..3
        atomicAdd(&hist[ld * 4 + sl], 1);
    }
    __syncthreads();
    int c0 = hist[t * 4 + 0], c1 = hist[t * 4 + 1];
    int c2 = hist[t * 4 + 2], c3 = hist[t * 4 + 3];
    int d = c0 + c1 + c2 + c3;                  // node degree
    nsum[t] = d;
    __syncthreads();
    for (int off = 1; off < 256; off <<= 1) {   // inclusive scan of node degrees
        int x = (t >= off) ? nsum[t - off] : 0;
        __syncthreads();
        nsum[t] += x;
        __syncthreads();
    }
    int excl = nsum[t] - d;
    // slice cursors (exclusive) for this node
    hist[t * 4 + 0] = excl;
    hist[t * 4 + 1] = excl + c0;
    hist[t * 4 + 2] = excl + c0 + c1;
    hist[t * 4 + 3] = excl + c0 + c1 + c2;
    __syncthreads();
    for (int i = t; i < ecnt; i += 256) {
        int p = packed[ebase + i];
        int ld = ((unsigned)p) >> 24;
        int srcv = p & 0xFFFFFF;
        int pos = atomicAdd(&hist[ld * 4 + (srcv >> 15)], 1);
        csr_l[pos] = srcv;
    }
    __syncthreads();
    for (int i = t; i < ecnt; i += 256)
        csr[ebase + i] = csr_l[i];
    if (t < nn) {
        offs_g[node0 + t] = ebase + excl;
        dinv[node0 + t] = rsqrtf((float)d + 1.0f);
    }
    if (b == NBK - 1 && t == 0) offs_g[N_NODES] = N_EDGES;
}

// ---------------- GEMM1 via MFMA fp16: h1s = fp16((x @ W1) * dinv[n]) ----------------
__global__ __launch_bounds__(256) void k_gemm1m(const float* __restrict__ x,
                                                const float* __restrict__ W1,
                                                const float* __restrict__ dinv,
                                                unsigned short* __restrict__ h1s) {
    __shared__ __align__(16) unsigned short xt[64 * KPAD];   // 33.8 KB fp16 [node][k]
    __shared__ __align__(16) unsigned short wtc[64 * WPAD];  // 5.1 KB fp16 [col][kk] per chunk
    int t = threadIdx.x;
    int lane = t & 63;
    int w = t >> 6;
    int nodeBase = blockIdx.x * 64;

    #pragma unroll
    for (int i = 0; i < 16; i++) {
        int f = i * 256 + t;
        int node = f >> 6;
        int pos = f & 63;
        int gn = nodeBase + node; if (gn >= N_NODES) gn = N_NODES - 1;
        float4 v = *(const float4*)(x + (size_t)gn * F_IN + pos * 4);
        ushort4 h;
        h.x = __half_as_ushort(__float2half(v.x));
        h.y = __half_as_ushort(__float2half(v.y));
        h.z = __half_as_ushort(__float2half(v.z));
        h.w = __half_as_ushort(__float2half(v.w));
        *(ushort4*)&xt[node * KPAD + pos * 4] = h;
    }
    f32x4 acc0 = {}, acc1 = {}, acc2 = {}, acc3 = {};
    __syncthreads();

    int am = lane & 15;
    int ag = lane >> 4;
    for (int kc = 0; kc < 8; kc++) {
        #pragma unroll
        for (int i = 0; i < 2; i++) {
            int f = i * 256 + t;
            int kk = f >> 4;
            int c4 = (f & 15) * 4;
            float4 v = *(const float4*)(W1 + (size_t)(kc * 32 + kk) * H1 + c4);
            wtc[(c4 + 0) * WPAD + kk] = __half_as_ushort(__float2half(v.x));
            wtc[(c4 + 1) * WPAD + kk] = __half_as_ushort(__float2half(v.y));
            wtc[(c4 + 2) * WPAD + kk] = __half_as_ushort(__float2half(v.z));
            wtc[(c4 + 3) * WPAD + kk] = __half_as_ushort(__float2half(v.w));
        }
        __syncthreads();
        f16x8 a = *(const f16x8*)&xt[(w * 16 + am) * KPAD + kc * 32 + ag * 8];
        f16x8 b0 = *(const f16x8*)&wtc[(0 * 16 + am) * WPAD + ag * 8];
        f16x8 b1 = *(const f16x8*)&wtc[(1 * 16 + am) * WPAD + ag * 8];
        f16x8 b2 = *(const f16x8*)&wtc[(2 * 16 + am) * WPAD + ag * 8];
        f16x8 b3 = *(const f16x8*)&wtc[(3 * 16 + am) * WPAD + ag * 8];
        acc0 = __builtin_amdgcn_mfma_f32_16x16x32_f16(a, b0, acc0, 0, 0, 0);
        acc1 = __builtin_amdgcn_mfma_f32_16x16x32_f16(a, b1, acc1, 0, 0, 0);
        acc2 = __builtin_amdgcn_mfma_f32_16x16x32_f16(a, b2, acc2, 0, 0, 0);
        acc3 = __builtin_amdgcn_mfma_f32_16x16x32_f16(a, b3, acc3, 0, 0, 0);
        __syncthreads();
    }

    #pragma unroll
    for (int r = 0; r < 4; r++) {
        int node = nodeBase + w * 16 + ag * 4 + r;
        if (node < N_NODES) {
            float dn = dinv[node];
            unsigned short* orow = &h1s[(size_t)node * H1];
            orow[ 0 + am] = __half_as_ushort(__float2half(acc0[r] * dn));
            orow[16 + am] = __half_as_ushort(__float2half(acc1[r] * dn));
            orow[32 + am] = __half_as_ushort(__float2half(acc2[r] * dn));
            orow[48 + am] = __half_as_ushort(__float2half(acc3[r] * dn));
        }
    }
}

// ---- fused agg1 + BN1 + ReLU + GEMM2 + dinv-scale: 32 lanes/node, 2 ch/lane, 16-unroll ----
// no block barrier between agg and gemm2: rows[slot] is produced+consumed by the same half-wave
__global__ __launch_bounds__(256) void k_agg1f(const unsigned short* __restrict__ h1s,
                                               const float* __restrict__ dinv,
                                               const int* __restrict__ offs,
                                               const int* __restrict__ csr,
                                               const float* __restrict__ b1,
                                               const float* __restrict__ g1,
                                               const float* __restrict__ be1,
                                               const float* __restrict__ m1,
                                               const float* __restrict__ v1,
                                               const float* __restrict__ W2,
                                               unsigned short* __restrict__ h2s) {
    __shared__ float w2[H1 * H2C];   // natural layout [c][j]
    __shared__ float rows[8][64];
    int t = threadIdx.x;
    for (int i = t; i < H1 * H2C; i += 256) w2[i] = W2[i];
    __syncthreads();

    int slot = t >> 5;
    int cp = t & 31;
    int n = blockIdx.x * 8 + slot;
    const ushort2* hp = (const ushort2*)h1s;   // [N][32]
    float sx = 0.f, sy = 0.f;
    int k = offs[n], kend = offs[n + 1];
    for (; k + 15 < kend; k += 16) {
        int s0 = csr[k],      s1 = csr[k + 1],  s2 = csr[k + 2],  s3 = csr[k + 3];
        int s4 = csr[k + 4],  s5 = csr[k + 5],  s6 = csr[k + 6],  s7 = csr[k + 7];
        int s8 = csr[k + 8],  s9 = csr[k + 9],  sa = csr[k + 10], sb = csr[k + 11];
        int sc = csr[k + 12], sd = csr[k + 13], se = csr[k + 14], sf = csr[k + 15];
        ushort2 u0 = hp[(size_t)s0 * 32 + cp], u1 = hp[(size_t)s1 * 32 + cp];
        ushort2 u2 = hp[(size_t)s2 * 32 + cp], u3 = hp[(size_t)s3 * 32 + cp];
        ushort2 u4 = hp[(size_t)s4 * 32 + cp], u5 = hp[(size_t)s5 * 32 + cp];
        ushort2 u6 = hp[(size_t)s6 * 32 + cp], u7 = hp[(size_t)s7 * 32 + cp];
        ushort2 u8 = hp[(size_t)s8 * 32 + cp], u9 = hp[(size_t)s9 * 32 + cp];
        ushort2 ua = hp[(size_t)sa * 32 + cp], ub = hp[(size_t)sb * 32 + cp];
        ushort2 uc = hp[(size_t)sc * 32 + cp], ud = hp[(size_t)sd * 32 + cp];
        ushort2 ue = hp[(size_t)se * 32 + cp], uf = hp[(size_t)sf * 32 + cp];
        float2 f0 = __half22float2(*(const __half2*)&u0);
        float2 f1 = __half22float2(*(const __half2*)&u1);
        float2 f2 = __half22float2(*(const __half2*)&u2);
        float2 f3 = __half22float2(*(const __half2*)&u3);
        float2 f4 = __half22float2(*(const __half2*)&u4);
        float2 f5 = __half22float2(*(const __half2*)&u5);
        float2 f6 = __half22float2(*(const __half2*)&u6);
        float2 f7 = __half22float2(*(const __half2*)&u7);
        float2 f8 = __half22float2(*(const __half2*)&u8);
        float2 f9 = __half22float2(*(const __half2*)&u9);
        float2 fa = __half22float2(*(const __half2*)&ua);
        float2 fb = __half22float2(*(const __half2*)&ub);
        float2 fc = __half22float2(*(const __half2*)&uc);
        float2 fd = __half22float2(*(const __half2*)&ud);
        float2 fe = __half22float2(*(const __half2*)&ue);
        float2 ff = __half22float2(*(const __half2*)&uf);
        sx += ((f0.x + f1.x) + (f2.x + f3.x)) + ((f4.x + f5.x) + (f6.x + f7.x))
            + ((f8.x + f9.x) + (fa.x + fb.x)) + ((fc.x + fd.x) + (fe.x + ff.x));
        sy += ((f0.y + f1.y) + (f2.y + f3.y)) + ((f4.y + f5.y) + (f6.y + f7.y))
            + ((f8.y + f9.y) + (fa.y + fb.y)) + ((fc.y + fd.y) + (fe.y + ff.y));
    }
    for (; k + 7 < kend; k += 8) {
        int s0 = csr[k],     s1 = csr[k + 1], s2 = csr[k + 2], s3 = csr[k + 3];
        int s4 = csr[k + 4], s5 = csr[k + 5], s6 = csr[k + 6], s7 = csr[k + 7];
        ushort2 u0 = hp[(size_t)s0 * 32 + cp], u1 = hp[(size_t)s1 * 32 + cp];
        ushort2 u2 = hp[(size_t)s2 * 32 + cp], u3 = hp[(size_t)s3 * 32 + cp];
        ushort2 u4 = hp[(size_t)s4 * 32 + cp], u5 = hp[(size_t)s5 * 32 + cp];
        ushort2 u6 = hp[(size_t)s6 * 32 + cp], u7 = hp[(size_t)s7 * 32 + cp];
        float2 f0 = __half22float2(*(const __half2*)&u0);
        float2 f1 = __half22float2(*(const __half2*)&u1);
        float2 f2 = __half22float2(*(const __half2*)&u2);
        float2 f3 = __half22float2(*(const __half2*)&u3);
        float2 f4 = __half22float2(*(const __half2*)&u4);
        float2 f5 = __half22float2(*(const __half2*)&u5);
        float2 f6 = __half22float2(*(const __half2*)&u6);
        float2 f7 = __half22float2(*(const __half2*)&u7);
        sx += (f0.x + f1.x) + (f2.x + f3.x) + ((f4.x + f5.x) + (f6.x + f7.x));
        sy += (f0.y + f1.y) + (f2.y + f3.y) + ((f4.y + f5.y) + (f6.y + f7.y));
    }
    if (k < kend) {
        int last = kend - 1;
        int i1 = k + 1 <= last ? k + 1 : last;
        int i2 = k + 2 <= last ? k + 2 : last;
        int i3 = k + 3 <= last ? k + 3 : last;
        int i4 = k + 4 <= last ? k + 4 : last;
        int i5 = k + 5 <= last ? k + 5 : last;
        int i6 = k + 6 <= last ? k + 6 : last;
        int s0 = csr[k],  s1 = csr[i1], s2 = csr[i2], s3 = csr[i3];
        int s4 = csr[i4], s5 = csr[i5], s6 = csr[i6];
        ushort2 u0 = hp[(size_t)s0 * 32 + cp], u1 = hp[(size_t)s1 * 32 + cp];
        ushort2 u2 = hp[(size_t)s2 * 32 + cp], u3 = hp[(size_t)s3 * 32 + cp];
        ushort2 u4 = hp[(size_t)s4 * 32 + cp], u5 = hp[(size_t)s5 * 32 + cp];
        ushort2 u6 = hp[(size_t)s6 * 32 + cp];
        float2 f0 = __half22float2(*(const __half2*)&u0);
        float2 f1 = __half22float2(*(const __half2*)&u1);
        float2 f2 = __half22float2(*(const __half2*)&u2);
        float2 f3 = __half22float2(*(const __half2*)&u3);
        float2 f4 = __half22float2(*(const __half2*)&u4);
        float2 f5 = __half22float2(*(const __half2*)&u5);
        float2 f6 = __half22float2(*(const __half2*)&u6);
        float m1v = (k + 1 <= last) ? 1.f : 0.f;
        float m2v = (k + 2 <= last) ? 1.f : 0.f;
        float m3v = (k + 3 <= last) ? 1.f : 0.f;
        float m4v = (k + 4 <= last) ? 1.f : 0.f;
        float m5v = (k + 5 <= last) ? 1.f : 0.f;
        float m6v = (k + 6 <= last) ? 1.f : 0.f;
        sx += f0.x + m1v * f1.x + m2v * f2.x + m3v * f3.x + m4v * f4.x + m5v * f5.x + m6v * f6.x;
        sy += f0.y + m1v * f1.y + m2v * f2.y + m3v * f3.y + m4v * f4.y + m5v * f5.y + m6v * f6.y;
    }
    // self term (pre-scaled by dinv[n]) + BN1 + ReLU
    ushort2 su = hp[(size_t)n * 32 + cp];
    float2 sf2 = __half22float2(*(const __half2*)&su);
    float dn = dinv[n];
    int c0 = cp * 2, c1 = c0 + 1;
    float r0 = (sx + sf2.x) * dn + b1[c0];
    float r1 = (sy + sf2.y) * dn + b1[c1];
    r0 = (r0 - m1[c0]) * rsqrtf(v1[c0] + EPS) * g1[c0] + be1[c0];
    r1 = (r1 - m1[c1]) * rsqrtf(v1[c1] + EPS) * g1[c1] + be1[c1];
    rows[slot][c0] = fmaxf(r0, 0.f);
    rows[slot][c1] = fmaxf(r1, 0.f);
    __builtin_amdgcn_wave_barrier();   // same-wave LDS RAW; no block barrier needed
    const float4* rp = (const float4*)rows[slot];
    float acc = 0.f;
    #pragma unroll
    for (int q = 0; q < 16; q++) {
        float4 rv = rp[q];
        int kb = q * 4;
        acc += rv.x * w2[(kb + 0) * H2C + cp] + rv.y * w2[(kb + 1) * H2C + cp]
             + rv.z * w2[(kb + 2) * H2C + cp] + rv.w * w2[(kb + 3) * H2C + cp];
    }
    h2s[(size_t)n * H2C + cp] = __half_as_ushort(__float2half(acc * dn));
}

// ---------------- agg2 + BN2 + ReLU + linear: 16 lanes/node, 2 ch/lane, 16-unroll ----------------
__global__ __launch_bounds__(256) void k_agg2(const unsigned short* __restrict__ h2s,
                                              const float* __restrict__ dinv,
                                              const int* __restrict__ offs,
                                              const int* __restrict__ csr,
                                              const float* __restrict__ b2,
                                              const float* __restrict__ g2,
                                              const float* __restrict__ be2,
                                              const float* __restrict__ m2,
                                              const float* __restrict__ v2,
                                              const float* __restrict__ Wl,
                                              const float* __restrict__ bl,
                                              float* __restrict__ out) {
    int gid = blockIdx.x * 256 + threadIdx.x;
    int n = gid >> 4;
    int cp = gid & 15;
    if (n >= N_NODES) return;
    const ushort2* hp = (const ushort2*)h2s;   // [N][16]
    float sx = 0.f, sy = 0.f;
    int k = offs[n], kend = offs[n + 1];
    for (; k + 15 < kend; k += 16) {
        int s0 = csr[k],      s1 = csr[k + 1],  s2 = csr[k + 2],  s3 = csr[k + 3];
        int s4 = csr[k + 4],  s5 = csr[k + 5],  s6 = csr[k + 6],  s7 = csr[k + 7];
        int s8 = csr[k + 8],  s9 = csr[k + 9],  sa = csr[k + 10], sb = csr[k + 11];
        int sc = csr[k + 12], sd = csr[k + 13], se = csr[k + 14], sf = csr[k + 15];
        ushort2 u0 = hp[(size_t)s0 * 16 + cp], u1 = hp[(size_t)s1 * 16 + cp];
        ushort2 u2 = hp[(size_t)s2 * 16 + cp], u3 = hp[(size_t)s3 * 16 + cp];
        ushort2 u4 = hp[(size_t)s4 * 16 + cp], u5 = hp[(size_t)s5 * 16 + cp];
        ushort2 u6 = hp[(size_t)s6 * 16 + cp], u7 = hp[(size_t)s7 * 16 + cp];
        ushort2 u8 = hp[(size_t)s8 * 16 + cp], u9 = hp[(size_t)s9 * 16 + cp];
        ushort2 ua = hp[(size_t)sa * 16 + cp], ub = hp[(size_t)sb * 16 + cp];
        ushort2 uc = hp[(size_t)sc * 16 + cp], ud = hp[(size_t)sd * 16 + cp];
        ushort2 ue = hp[(size_t)se * 16 + cp], uf = hp[(size_t)sf * 16 + cp];
        float2 f0 = __half22float2(*(const __half2*)&u0);
        float2 f1 = __half22float2(*(const __half2*)&u1);
        float2 f2 = __half22float2(*(const __half2*)&u2);
        float2 f3 = __half22float2(*(const __half2*)&u3);
        float2 f4 = __half22float2(*(const __half2*)&u4);
        float2 f5 = __half22float2(*(const __half2*)&u5);
        float2 f6 = __half22float2(*(const __half2*)&u6);
        float2 f7 = __half22float2(*(const __half2*)&u7);
        float2 f8 = __half22float2(*(const __half2*)&u8);
        float2 f9 = __half22float2(*(const __half2*)&u9);
        float2 fa = __half22float2(*(const __half2*)&ua);
        float2 fb = __half22float2(*(const __half2*)&ub);
        float2 fc = __half22float2(*(const __half2*)&uc);
        float2 fd = __half22float2(*(const __half2*)&ud);
        float2 fe = __half22float2(*(const __half2*)&ue);
        float2 ff = __half22float2(*(const __half2*)&uf);
        sx += ((f0.x + f1.x) + (f2.x + f3.x)) + ((f4.x + f5.x) + (f6.x + f7.x))
            + ((f8.x + f9.x) + (fa.x + fb.x)) + ((fc.x + fd.x) + (fe.x + ff.x));
        sy += ((f0.y + f1.y) + (f2.y + f3.y)) + ((f4.y + f5.y) + (f6.y + f7.y))
            + ((f8.y + f9.y) + (fa.y + fb.y)) + ((fc.y + fd.y) + (fe.y + ff.y));
    }
    for (; k + 7 < kend; k += 8) {
        int s0 = csr[k],     s1 = csr[k + 1], s2 = csr[k + 2], s3 = csr[k + 3];
        int s4 = csr[k + 4], s5 = csr[k + 5], s6 = csr[k + 6], s7 = csr[k + 7];
        ushort2 u0 = hp[(size_t)s0 * 16 + cp], u1 = hp[(size_t)s1 * 16 + cp];
        ushort2 u2 = hp[(size_t)s2 * 16 + cp], u3 = hp[(size_t)s3 * 16 + cp];
        ushort2 u4 = hp[(size_t)s4 * 16 + cp], u5 = hp[(size_t)s5 * 16 + cp];
        ushort2 u6 = hp[(size_t)s6 * 16 + cp], u7 = hp[(size_t)s7 * 16 + cp];
        float2 f0 = __half22float2(*(const __half2*)&u0);
        float2 f1 = __half22float2(*(const __half2*)&u1);
        float2 f2 = __half22float2(*(const __half2*)&u2);
        float2 f3 = __half22float2(*(const __half2*)&u3);
        float2 f4 = __half22float2(*(const __half2*)&u4);
        float2 f5 = __half22float2(*(const __half2*)&u5);
        float2 f6 = __half22float2(*(const __half2*)&u6);
        float2 f7 = __half22float2(*(const __half2*)&u7);
        sx += (f0.x + f1.x) + (f2.x + f3.x) + ((f4.x + f5.x) + (f6.x + f7.x));
        sy += (f0.y + f1.y) + (f2.y + f3.y) + ((f4.y + f5.y) + (f6.y + f7.y));
    }
    if (k < kend) {
        int last = kend - 1;
        int i1 = k + 1 <= last ? k + 1 : last;
        int i2 = k + 2 <= last ? k + 2 : last;
        int i3 = k + 3 <= last ? k + 3 : last;
        int i4 = k + 4 <= last ? k + 4 : last;
        int i5 = k + 5 <= last ? k + 5 : last;
        int i6 = k + 6 <= last ? k + 6 : last;
        int s0 = csr[k],  s1 = csr[i1], s2 = csr[i2], s3 = csr[i3];
        int s4 = csr[i4], s5 = csr[i5], s6 = csr[i6];
        ushort2 u0 = hp[(size_t)s0 * 16 + cp], u1 = hp[(size_t)s1 * 16 + cp];
        ushort2 u2 = hp[(size_t)s2 * 16 + cp], u3 = hp[(size_t)s3 * 16 + cp];
        ushort2 u4 = hp[(size_t)s4 * 16 + cp], u5 = hp[(size_t)s5 * 16 + cp];
        ushort2 u6 = hp[(size_t)s6 * 16 + cp];
        float2 f0 = __half22float2(*(const __half2*)&u0);
        float2 f1 = __half22float2(*(const __half2*)&u1);
        float2 f2 = __half22float2(*(const __half2*)&u2);
        float2 f3 = __half22float2(*(const __half2*)&u3);
        float2 f4 = __half22float2(*(const __half2*)&u4);
        float2 f5 = __half22float2(*(const __half2*)&u5);
        float2 f6 = __half22float2(*(const __half2*)&u6);
        float m1v = (k + 1 <= last) ? 1.f : 0.f;
        float m2v = (k + 2 <= last) ? 1.f : 0.f;
        float m3v = (k + 3 <= last) ? 1.f : 0.f;
        float m4v = (k + 4 <= last) ? 1.f : 0.f;
        float m5v = (k + 5 <= last) ? 1.f : 0.f;
        float m6v = (k + 6 <= last) ? 1.f : 0.f;
        sx += f0.x + m1v * f1.x + m2v * f2.x + m3v * f3.x + m4v * f4.x + m5v * f5.x + m6v * f6.x;
        sy += f0.y + m1v * f1.y + m2v * f2.y + m3v * f3.y + m4v * f4.y + m5v * f5.y + m6v * f6.y;
    }
    ushort2 su = hp[(size_t)n * 16 + cp];
    float2 sf2 = __half22float2(*(const __half2*)&su);
    float dn = dinv[n];
    int c0 = cp * 2, c1 = c0 + 1;
    float r0 = (sx + sf2.x) * dn + b2[c0];
    float r1 = (sy + sf2.y) * dn + b2[c1];
    r0 = (r0 - m2[c0]) * rsqrtf(v2[c0] + EPS) * g2[c0] + be2[c0];
    r1 = (r1 - m2[c1]) * rsqrtf(v2[c1] + EPS) * g2[c1] + be2[c1];
    r0 = fmaxf(r0, 0.f);
    r1 = fmaxf(r1, 0.f);
    float p0 = r0 * Wl[c0 * 2 + 0] + r1 * Wl[c1 * 2 + 0];
    float p1 = r0 * Wl[c0 * 2 + 1] + r1 * Wl[c1 * 2 + 1];
    #pragma unroll
    for (int off = 8; off > 0; off >>= 1) {
        p0 += __shfl_xor(p0, off);
        p1 += __shfl_xor(p1, off);
    }
    if (cp == 0) {
        *(float2*)&out[(size_t)n * NCLS] = make_float2(p0 + bl[0], p1 + bl[1]);
    }
}

extern "C" void kernel_launch(void* const* d_in, const int* in_sizes, int n_in,
                              void* d_out, int out_size, void* d_ws, size_t ws_size,
                              hipStream_t stream) {
    const float* x   = (const float*)d_in[0];
    const int*   ei  = (const int*)d_in[1];
    const int*   src = ei;
    const int*   dst = ei + N_EDGES;
    const float* W1  = (const float*)d_in[2];
    const float* b1  = (const float*)d_in[3];
    const float* g1  = (const float*)d_in[4];
    const float* be1 = (const float*)d_in[5];
    const float* m1  = (const float*)d_in[6];
    const float* v1  = (const float*)d_in[7];
    const float* W2  = (const float*)d_in[8];
    const float* b2  = (const float*)d_in[9];
    const float* g2  = (const float*)d_in[10];
    const float* be2 = (const float*)d_in[11];
    const float* m2  = (const float*)d_in[12];
    const float* v2  = (const float*)d_in[13];
    const float* Wl  = (const float*)d_in[14];
    const float* bl  = (const float*)d_in[15];
    float* out = (float*)d_out;

    char* p = (char*)d_ws;
    int*   bucket_count = (int*)p;  p += 1600;                     // NBK ints (+pad)
    int*   cursor       = (int*)p;  p += 1600;                     // NBK ints
    int*   bucket_base  = (int*)p;  p += 1600;                     // NBK+1 ints
    int*   offs         = (int*)p;  p += 400016;                   // N+1 ints
    float* dinv         = (float*)p; p += 400000;                  // N floats
    int*   packed       = (int*)p;  p += (size_t)N_EDGES * 4;      // E ints
    int*   csr          = (int*)p;  p += (size_t)N_EDGES * 4;      // E ints
    unsigned short* h1s = (unsigned short*)p; p += (size_t)N_NODES * H1 * 2;   // fp16 [N][64], dinv-scaled
    unsigned short* h2s = (unsigned short*)p; p += (size_t)N_NODES * H2C * 2;  // fp16 [N][32], dinv-scaled

    hipMemsetAsync(bucket_count, 0, 3200, stream);   // bucket_count + cursor

    k_bin_count<<<512, 256, 0, stream>>>(dst, bucket_count);
    k_bucket_scan<<<1, 512, 0, stream>>>(bucket_count, bucket_base);
    k_bin_scatter<<<(N_EDGES + SCHUNK - 1) / SCHUNK, 256, 0, stream>>>(src, dst, bucket_base, cursor, packed);
    k_csr_build<<<NBK, 256, 0, stream>>>(packed, bucket_base, csr, offs, dinv);
    k_gemm1m<<<(N_NODES + 63) / 64, 256, 0, stream>>>(x, W1, dinv, h1s);
    k_agg1f<<<N_NODES / 8, 256, 0, stream>>>(h1s, dinv, offs, csr, b1, g1, be1, m1, v1, W2, h2s);
    k_agg2<<<(N_NODES * 16) / 256, 256, 0, stream>>>(h2s, dinv, offs, csr, b2, g2, be2, m2, v2, Wl, bl, out);
}